// Round 12
// baseline (599.256 us; speedup 1.0000x reference)
//
#include <hip/hip_runtime.h>
#include <hip/hip_fp16.h>

#define H 64
#define CIN 32
#define TWOH 128
#define NGRAPH 64

// bucketed CSR build
#define BSH 7
#define BNODE 128
#define NBLK_PART 256
#define BCAP 32
#define MAXNB 2048
#define OCAP 65536

typedef unsigned short bfraw;
typedef short v8s __attribute__((ext_vector_type(8)));
typedef float v4f __attribute__((ext_vector_type(4)));

__device__ __forceinline__ float bf2f(bfraw u) {
    return __uint_as_float(((unsigned)u) << 16);
}
__device__ __forceinline__ bfraw f2bf(float f) {
    unsigned u = __float_as_uint(f);
    unsigned r = (u + 0x7fffu + ((u >> 16) & 1u)) >> 16;  // RNE
    return (bfraw)r;
}
// split fp32 -> hi + lo bf16 (combined rel err ~2^-17)
__device__ __forceinline__ void f2bf2(float f, bfraw& hi, bfraw& lo) {
    hi = f2bf(f);
    lo = f2bf(f - bf2f(hi));
}
// fp16 raw bits (RNE)
__device__ __forceinline__ bfraw f2h(float f) {
    return __half_as_ushort(__float2half(f));
}
__device__ __forceinline__ __half2 u2h2(unsigned u) {
    union { unsigned u; __half2 h; } c; c.u = u; return c.h;
}

// ----- MFMA input GEMM: x0[N,64] = x[N,32] @ Win + bin; xh = fp16(relu(x0)) -----
extern "C" __global__ void __launch_bounds__(256) k_input_gemm(
    const float* __restrict__ x, const float* __restrict__ Win,
    const float* __restrict__ bin, float* __restrict__ x0,
    bfraw* __restrict__ xh, int N)
{
    const int lane = threadIdx.x & 63;
    const int row = lane & 15;
    const int kg  = lane >> 4;
    // B fragments: Win[32][64] split hi/lo, 1 k-chunk (K=32), 4 col-tiles
    v8s bhi[4], blo[4];
    #pragma unroll
    for (int ct = 0; ct < 4; ++ct) {
        v8s bh, bl;
        #pragma unroll
        for (int i = 0; i < 8; ++i) {
            const float w = Win[(kg * 8 + i) * H + ct * 16 + row];
            bfraw h, l; f2bf2(w, h, l);
            bh[i] = (short)h; bl[i] = (short)l;
        }
        bhi[ct] = bh; blo[ct] = bl;
    }
    float bcol[4];
    #pragma unroll
    for (int ct = 0; ct < 4; ++ct) bcol[ct] = bin[ct * 16 + row];

    const int wpb = blockDim.x >> 6;
    const int wid = blockIdx.x * wpb + (threadIdx.x >> 6);
    const int wstride = gridDim.x * wpb;
    const int tiles = (N + 15) >> 4;
    for (int t = wid; t < tiles; t += wstride) {
        const int tb = t << 4;
        int nA = tb + row; if (nA >= N) nA = N - 1;
        v8s ah, al;
        #pragma unroll
        for (int i = 0; i < 8; ++i) {
            const float v = x[(size_t)nA * CIN + kg * 8 + i];
            bfraw h, l; f2bf2(v, h, l);
            ah[i] = (short)h; al[i] = (short)l;
        }
        v4f c[4];
        #pragma unroll
        for (int ct = 0; ct < 4; ++ct) {
            v4f cc = (v4f){0.f, 0.f, 0.f, 0.f};
            cc = __builtin_amdgcn_mfma_f32_16x16x32_bf16(ah, bhi[ct], cc, 0, 0, 0);
            cc = __builtin_amdgcn_mfma_f32_16x16x32_bf16(ah, blo[ct], cc, 0, 0, 0);
            cc = __builtin_amdgcn_mfma_f32_16x16x32_bf16(al, bhi[ct], cc, 0, 0, 0);
            c[ct] = cc;
        }
        #pragma unroll
        for (int ct = 0; ct < 4; ++ct) {
            #pragma unroll
            for (int r = 0; r < 4; ++r) {
                const int node = tb + kg * 4 + r;
                if (node < N) {
                    const float v = c[ct][r] + bcol[ct];
                    const size_t idx = (size_t)node * H + ct * 16 + row;
                    x0[idx] = v;
                    xh[idx] = f2h(fmaxf(v, 0.f));   // relu pre-folded, fp16
                }
            }
        }
    }
}

// ---------------- weight conversion to split bf16 (all layers, once) ----------------
extern "C" __global__ void k_cvtw(const float* __restrict__ W1s,
    const float* __restrict__ W2s, bfraw* __restrict__ W1hi,
    bfraw* __restrict__ W1lo, bfraw* __restrict__ W2hi,
    bfraw* __restrict__ W2lo, int total)  // total = L*H*TWOH
{
    int i = blockIdx.x * blockDim.x + threadIdx.x;
    const int st = gridDim.x * blockDim.x;
    for (; i < total; i += st) {
        bfraw h, l;
        f2bf2(W1s[i], h, l); W1hi[i] = h; W1lo[i] = l;
        f2bf2(W2s[i], h, l); W2hi[i] = h; W2lo[i] = l;
    }
}

// ---------------- block-private bucket partition (pass A) ----------------
__device__ __forceinline__ void bput(int s, int d, unsigned* __restrict__ lcnt,
    unsigned* __restrict__ myTmp, unsigned* __restrict__ deg,
    int* __restrict__ oflow, unsigned* __restrict__ ocnt)
{
    const int b = d >> BSH;
    const unsigned pos = atomicAdd(&lcnt[b], 1u);   // LDS atomic
    if (pos < BCAP) {
        myTmp[b * BCAP + pos] = (unsigned)s | ((unsigned)(d & (BNODE - 1)) << 20);
    } else {
        const unsigned o = atomicAdd(ocnt, 1u);
        if (o < OCAP) {
            oflow[2 * o] = s; oflow[2 * o + 1] = d;
            atomicAdd(&deg[d], 1u);
        }
    }
}

extern "C" __global__ void __launch_bounds__(256) k_bucket(
    const int* __restrict__ src, const int* __restrict__ dst,
    unsigned* __restrict__ bcnt, unsigned* __restrict__ btmp,
    unsigned* __restrict__ deg, int* __restrict__ oflow,
    unsigned* __restrict__ ocnt, int E, int NBck)
{
    __shared__ unsigned lcnt[MAXNB];  // 8 KB (NBck <= 2048)
    for (int i = threadIdx.x; i < NBck; i += blockDim.x) lcnt[i] = 0u;
    __syncthreads();
    unsigned* __restrict__ myTmp = btmp + (size_t)blockIdx.x * NBck * BCAP;
    const int tid0 = blockIdx.x * blockDim.x + threadIdx.x;
    const int st = gridDim.x * blockDim.x;
    const int E4 = E >> 2;
    const int4* s4 = (const int4*)src;
    const int4* d4 = (const int4*)dst;
    for (int j = tid0; j < E4; j += st) {
        const int4 sv = s4[j];
        const int4 dv = d4[j];
        bput(sv.x, dv.x, lcnt, myTmp, deg, oflow, ocnt);
        bput(sv.y, dv.y, lcnt, myTmp, deg, oflow, ocnt);
        bput(sv.z, dv.z, lcnt, myTmp, deg, oflow, ocnt);
        bput(sv.w, dv.w, lcnt, myTmp, deg, oflow, ocnt);
    }
    for (int j = (E4 << 2) + tid0; j < E; j += st)
        bput(src[j], dst[j], lcnt, myTmp, deg, oflow, ocnt);
    __syncthreads();
    unsigned* __restrict__ myCnt = bcnt + (size_t)blockIdx.x * NBck;
    for (int i = threadIdx.x; i < NBck; i += blockDim.x) {
        const unsigned c = lcnt[i];
        myCnt[i] = (c < BCAP) ? c : BCAP;
    }
}

// ---------------- per-bucket degree histogram ----------------
extern "C" __global__ void __launch_bounds__(256) k_bhist(
    const unsigned* __restrict__ bcnt, const unsigned* __restrict__ btmp,
    unsigned* __restrict__ deg, int N, int NBck)
{
    __shared__ unsigned hist[BNODE];
    const int b = blockIdx.x;
    for (int i = threadIdx.x; i < BNODE; i += blockDim.x) hist[i] = 0u;
    __syncthreads();
    for (int blk = threadIdx.x; blk < NBLK_PART; blk += blockDim.x) {
        const unsigned cnt = bcnt[(size_t)blk * NBck + b];
        const unsigned* p = btmp + ((size_t)blk * NBck + b) * BCAP;
        for (unsigned j = 0; j < cnt; ++j)
            atomicAdd(&hist[p[j] >> 20], 1u);
    }
    __syncthreads();
    const int base = b << BSH;
    for (int i = threadIdx.x; i < BNODE; i += blockDim.x)
        if (base + i < N) {
            const unsigned h = hist[i];
            if (h) atomicAdd(&deg[base + i], h);
        }
}

extern "C" __global__ void k_scan1(const unsigned* __restrict__ deg,
    unsigned* __restrict__ indptr, unsigned* __restrict__ bsum, int N)
{
    __shared__ unsigned s[256];
    const int tid = threadIdx.x;
    const int base = blockIdx.x * 1024 + tid * 4;
    unsigned d[4];
    #pragma unroll
    for (int j = 0; j < 4; ++j)
        d[j] = (base + j < N) ? ((deg[base + j] + 3u) & ~3u) : 0u;  // padded
    unsigned t = d[0] + d[1] + d[2] + d[3];
    s[tid] = t;
    __syncthreads();
    for (int o = 1; o < 256; o <<= 1) {
        unsigned v = (tid >= o) ? s[tid - o] : 0u;
        __syncthreads();
        s[tid] += v;
        __syncthreads();
    }
    unsigned run = (tid == 0) ? 0u : s[tid - 1];
    if (tid == 255) bsum[blockIdx.x] = s[255];
    #pragma unroll
    for (int j = 0; j < 4; ++j) {
        if (base + j < N) indptr[base + j] = run;
        run += d[j];
    }
}

extern "C" __global__ void k_scan2(unsigned* bsum, int nb,
    unsigned* __restrict__ indptr, int N)
{
    if (threadIdx.x == 0) {
        unsigned run = 0;
        for (int i = 0; i < nb; ++i) { unsigned v = bsum[i]; bsum[i] = run; run += v; }
        indptr[N] = run;  // total padded edges
    }
}

extern "C" __global__ void k_scan3(unsigned* __restrict__ indptr,
    const unsigned* __restrict__ bsum, unsigned* __restrict__ cursor, int N)
{
    const int base = blockIdx.x * 1024 + threadIdx.x * 4;
    const unsigned boff = bsum[blockIdx.x];
    #pragma unroll
    for (int j = 0; j < 4; ++j) {
        const int idx = base + j;
        if (idx < N) {
            const unsigned v = indptr[idx] + boff;
            indptr[idx] = v;
            cursor[idx] = v;
        }
    }
}

// ---------------- per-bucket scatter to final CSR (pass B) ----------------
extern "C" __global__ void __launch_bounds__(256) k_bscat(
    const unsigned* __restrict__ bcnt, const unsigned* __restrict__ btmp,
    const unsigned* __restrict__ indptr, unsigned* __restrict__ cursor,
    int* __restrict__ esrc, int N, int NBck)
{
    __shared__ unsigned lcur[BNODE];
    const int b = blockIdx.x;
    const int base = b << BSH;
    for (int i = threadIdx.x; i < BNODE; i += blockDim.x)
        lcur[i] = (base + i < N) ? indptr[base + i] : 0u;
    __syncthreads();
    for (int blk = threadIdx.x; blk < NBLK_PART; blk += blockDim.x) {
        const unsigned cnt = bcnt[(size_t)blk * NBck + b];
        const unsigned* p = btmp + ((size_t)blk * NBck + b) * BCAP;
        for (unsigned j = 0; j < cnt; ++j) {
            const unsigned e = p[j];
            const unsigned pos = atomicAdd(&lcur[e >> 20], 1u);
            esrc[pos] = (int)(e & 0xFFFFFu);
        }
    }
    __syncthreads();
    for (int i = threadIdx.x; i < BNODE; i += blockDim.x)
        if (base + i < N) cursor[base + i] = lcur[i];
}

// overflow edges (expected none) via global cursor
extern "C" __global__ void k_over(const int* __restrict__ oflow,
    const unsigned* __restrict__ ocnt, unsigned* __restrict__ cursor,
    int* __restrict__ esrc)
{
    unsigned n = *ocnt; if (n > OCAP) n = OCAP;
    int i = blockIdx.x * blockDim.x + threadIdx.x;
    const int st = gridDim.x * blockDim.x;
    for (; (unsigned)i < n; i += st) {
        const int s = oflow[2 * i], d = oflow[2 * i + 1];
        const unsigned pos = atomicAdd(&cursor[d], 1u);
        esrc[pos] = s;
    }
}

// fill padded slots with sentinel N (zero row)
extern "C" __global__ void k_pad(const unsigned* __restrict__ cursor,
    const unsigned* __restrict__ indptr, int* __restrict__ esrc, int N)
{
    int n = blockIdx.x * blockDim.x + threadIdx.x;
    const int st = gridDim.x * blockDim.x;
    for (; n < N; n += st) {
        const unsigned end = indptr[n + 1];
        for (unsigned p = cursor[n]; p < end; ++p) esrc[p] = N;
    }
}

// --- gather: hpre = (1+eps)*x0 + sum xh[src] (fp16, already relu'd); split bf16 ---
extern "C" __global__ void __launch_bounds__(256) k_agg(
    const float* __restrict__ x0, const bfraw* __restrict__ xh,
    const int* __restrict__ esrc, const unsigned* __restrict__ indptr,
    const float* __restrict__ epsp, bfraw* __restrict__ hprehi,
    bfraw* __restrict__ hprelo, int N)
{
    const int lane = threadIdx.x & 63;
    const int sub = lane >> 4;          // 0..3 : which edge of the group
    const int fi = (lane & 15) << 2;    // feature base (4 features)
    const int wpb = blockDim.x >> 6;
    int w = blockIdx.x * wpb + (threadIdx.x >> 6);
    const int wstride = gridDim.x * wpb;
    const float ep = 1.f + epsp[0];
    for (int n = w; n < N; n += wstride) {
        const unsigned s0 = indptr[n];
        const unsigned s1 = indptr[n + 1];   // padded: (s1-s0)%4==0
        float a0 = 0.f, a1 = 0.f, a2 = 0.f, a3 = 0.f;
        unsigned e = s0;
        // 32 edges / iter: 8 rows per lane, packed fp16 accumulate + f32 flush
        for (; e + 32 <= s1; e += 32) {
            int idx[8];
            #pragma unroll
            for (int j = 0; j < 8; ++j) idx[j] = esrc[e + 4 * j + sub];
            uint2 r[8];
            #pragma unroll
            for (int j = 0; j < 8; ++j)
                r[j] = *(const uint2*)&xh[(size_t)idx[j] * H + fi];
            __half2 s01 = u2h2(r[0].x);
            __half2 s23 = u2h2(r[0].y);
            #pragma unroll
            for (int j = 1; j < 8; ++j) {
                s01 = __hadd2(s01, u2h2(r[j].x));
                s23 = __hadd2(s23, u2h2(r[j].y));
            }
            const float2 f01 = __half22float2(s01);
            const float2 f23 = __half22float2(s23);
            a0 += f01.x; a1 += f01.y; a2 += f23.x; a3 += f23.y;
        }
        for (; e < s1; e += 4) {
            const int i0 = esrc[e + sub];
            const uint2 r = *(const uint2*)&xh[(size_t)i0 * H + fi];
            const float2 f01 = __half22float2(u2h2(r.x));
            const float2 f23 = __half22float2(u2h2(r.y));
            a0 += f01.x; a1 += f01.y; a2 += f23.x; a3 += f23.y;
        }
        #pragma unroll
        for (int o = 16; o < 64; o <<= 1) {
            a0 += __shfl_xor(a0, o);
            a1 += __shfl_xor(a1, o);
            a2 += __shfl_xor(a2, o);
            a3 += __shfl_xor(a3, o);
        }
        if (sub == 0) {
            const float4 self = *(const float4*)&x0[(size_t)n * H + fi];
            const float h0 = ep * self.x + a0;
            const float h1v = ep * self.y + a1;
            const float h2 = ep * self.z + a2;
            const float h3 = ep * self.w + a3;
            ushort4 ohi, olo;
            f2bf2(h0, ohi.x, olo.x);
            f2bf2(h1v, ohi.y, olo.y);
            f2bf2(h2, ohi.z, olo.z);
            f2bf2(h3, ohi.w, olo.w);
            *(ushort4*)&hprehi[(size_t)n * H + fi] = ohi;
            *(ushort4*)&hprelo[(size_t)n * H + fi] = olo;
        }
    }
}

// ------------- MFMA GEMM1 + BN stats: h1[N,128] = hpre @ W1 + b1 -------------
// split precision: C = Ahi*Whi + Ahi*Wlo + Alo*Whi. Each wave: half the cols.
extern "C" __global__ void __launch_bounds__(256) k_gemm1(
    const bfraw* __restrict__ hprehi, const bfraw* __restrict__ hprelo,
    const bfraw* __restrict__ W1hi, const bfraw* __restrict__ W1lo,
    const float* __restrict__ b1, float* __restrict__ h1,
    double* __restrict__ gsum, double* __restrict__ gsq, int N)
{
    __shared__ float ss[TWOH], sq[TWOH];
    if (threadIdx.x < TWOH) { ss[threadIdx.x] = 0.f; sq[threadIdx.x] = 0.f; }
    __syncthreads();
    const int lane = threadIdx.x & 63;
    const int row = lane & 15;   // A row / B col / D col
    const int kg  = lane >> 4;   // k-group
    const int wpb = blockDim.x >> 6;
    const int wid = blockIdx.x * wpb + (threadIdx.x >> 6);
    const int wstride = gridDim.x * wpb;
    const int half = wid & 1;          // which 64 of the 128 cols
    const int cb = half * 4;           // col-tile base
    // preload B fragments: 2 k-chunks x 4 col-tiles, hi+lo
    v8s bhi[2][4], blo[2][4];
    #pragma unroll
    for (int kc = 0; kc < 2; ++kc)
        #pragma unroll
        for (int ct = 0; ct < 4; ++ct) {
            v8s bh, bl;
            #pragma unroll
            for (int i = 0; i < 8; ++i) {
                const int idx = (kc * 32 + kg * 8 + i) * TWOH + (cb + ct) * 16 + row;
                bh[i] = (short)W1hi[idx];
                bl[i] = (short)W1lo[idx];
            }
            bhi[kc][ct] = bh; blo[kc][ct] = bl;
        }
    float bcol[4];
    #pragma unroll
    for (int ct = 0; ct < 4; ++ct) bcol[ct] = b1[(cb + ct) * 16 + row];

    const int tiles = (N + 15) >> 4;
    const int tstride = wstride >> 1;
    float sacc[4], qacc[4];
    #pragma unroll
    for (int ct = 0; ct < 4; ++ct) { sacc[ct] = 0.f; qacc[ct] = 0.f; }

    for (int t = wid >> 1; t < tiles; t += tstride) {
        const int tb = t << 4;
        int nA = tb + row; if (nA >= N) nA = N - 1;
        const v8s a0h = *(const v8s*)&hprehi[(size_t)nA * H + kg * 8];
        const v8s a1h = *(const v8s*)&hprehi[(size_t)nA * H + 32 + kg * 8];
        const v8s a0l = *(const v8s*)&hprelo[(size_t)nA * H + kg * 8];
        const v8s a1l = *(const v8s*)&hprelo[(size_t)nA * H + 32 + kg * 8];
        v4f c[4];
        #pragma unroll
        for (int ct = 0; ct < 4; ++ct) {
            v4f cc = (v4f){0.f, 0.f, 0.f, 0.f};
            cc = __builtin_amdgcn_mfma_f32_16x16x32_bf16(a0h, bhi[0][ct], cc, 0, 0, 0);
            cc = __builtin_amdgcn_mfma_f32_16x16x32_bf16(a1h, bhi[1][ct], cc, 0, 0, 0);
            cc = __builtin_amdgcn_mfma_f32_16x16x32_bf16(a0h, blo[0][ct], cc, 0, 0, 0);
            cc = __builtin_amdgcn_mfma_f32_16x16x32_bf16(a1h, blo[1][ct], cc, 0, 0, 0);
            cc = __builtin_amdgcn_mfma_f32_16x16x32_bf16(a0l, bhi[0][ct], cc, 0, 0, 0);
            cc = __builtin_amdgcn_mfma_f32_16x16x32_bf16(a1l, bhi[1][ct], cc, 0, 0, 0);
            c[ct] = cc;
        }
        #pragma unroll
        for (int ct = 0; ct < 4; ++ct) {
            #pragma unroll
            for (int r = 0; r < 4; ++r) {
                const int node = tb + kg * 4 + r;  // D row
                if (node < N) {
                    const float v = c[ct][r] + bcol[ct];
                    h1[(size_t)node * TWOH + (cb + ct) * 16 + row] = v;
                    sacc[ct] += v;
                    qacc[ct] += v * v;
                }
            }
        }
    }
    #pragma unroll
    for (int ct = 0; ct < 4; ++ct) {
        float s = sacc[ct];
        s += __shfl_xor(s, 16); s += __shfl_xor(s, 32);
        float q = qacc[ct];
        q += __shfl_xor(q, 16); q += __shfl_xor(q, 32);
        if (kg == 0) {
            atomicAdd(&ss[(cb + ct) * 16 + row], s);
            atomicAdd(&sq[(cb + ct) * 16 + row], q);
        }
    }
    __syncthreads();
    if (threadIdx.x < TWOH) {
        atomicAdd(&gsum[threadIdx.x], (double)ss[threadIdx.x]);
        atomicAdd(&gsq[threadIdx.x], (double)sq[threadIdx.x]);
    }
}

// ---------------- BN finalize: scale/shift ----------------
extern "C" __global__ void k_bnfin(const double* __restrict__ gsum,
    const double* __restrict__ gsq, const float* __restrict__ gamma,
    const float* __restrict__ beta, float* __restrict__ scsh, int N)
{
    const int j = threadIdx.x;
    if (j < TWOH) {
        const double mu = gsum[j] / N;
        const double var = gsq[j] / N - mu * mu;
        const float sc = gamma[j] * rsqrtf(fmaxf((float)var, 0.f) + 1e-5f);
        scsh[j] = sc;
        scsh[TWOH + j] = beta[j] - (float)mu * sc;
    }
}

// --- MFMA GEMM2 + fused BN/ReLU + residual: x0 += relu(h1*sc+sh) @ W2 + b2 ---
extern "C" __global__ void __launch_bounds__(256) k_gemm2(
    const float* __restrict__ h1, const float* __restrict__ scsh,
    const bfraw* __restrict__ W2hi, const bfraw* __restrict__ W2lo,
    const float* __restrict__ b2, float* __restrict__ x0,
    bfraw* __restrict__ xh, int N)
{
    __shared__ float scl[TWOH], shl[TWOH];  // 1 KB
    for (int i = threadIdx.x; i < TWOH; i += blockDim.x) {
        scl[i] = scsh[i];
        shl[i] = scsh[TWOH + i];
    }
    __syncthreads();
    const int lane = threadIdx.x & 63;
    const int row = lane & 15;
    const int kg  = lane >> 4;
    const int wpb = blockDim.x >> 6;
    const int wid = blockIdx.x * wpb + (threadIdx.x >> 6);
    const int wstride = gridDim.x * wpb;
    const int half = wid & 1;       // which 32 of the 64 cols
    const int cb = half * 2;        // col-tile base
    // preload B fragments: 4 k-chunks x 2 col-tiles, hi+lo
    v8s bhi[4][2], blo[4][2];
    #pragma unroll
    for (int kc = 0; kc < 4; ++kc)
        #pragma unroll
        for (int ct = 0; ct < 2; ++ct) {
            v8s bh, bl;
            #pragma unroll
            for (int i = 0; i < 8; ++i) {
                const int idx = (kc * 32 + kg * 8 + i) * H + (cb + ct) * 16 + row;
                bh[i] = (short)W2hi[idx];
                bl[i] = (short)W2lo[idx];
            }
            bhi[kc][ct] = bh; blo[kc][ct] = bl;
        }
    float bcol[2];
    #pragma unroll
    for (int ct = 0; ct < 2; ++ct) bcol[ct] = b2[(cb + ct) * 16 + row];
    // per-lane BN constants for this lane's 32 features (8 per k-chunk)
    float lsc[4][8], lsh[4][8];
    #pragma unroll
    for (int kc = 0; kc < 4; ++kc) {
        const int fb = kc * 32 + kg * 8;
        #pragma unroll
        for (int i = 0; i < 8; ++i) { lsc[kc][i] = scl[fb + i]; lsh[kc][i] = shl[fb + i]; }
    }

    const int tiles = (N + 15) >> 4;
    const int tstride = wstride >> 1;

    for (int t = wid >> 1; t < tiles; t += tstride) {
        const int tb = t << 4;
        int nA = tb + row; if (nA >= N) nA = N - 1;
        v8s ah[4], al[4];
        #pragma unroll
        for (int kc = 0; kc < 4; ++kc) {
            const int fb = kc * 32 + kg * 8;
            const float4 h0 = *(const float4*)&h1[(size_t)nA * TWOH + fb];
            const float4 h4 = *(const float4*)&h1[(size_t)nA * TWOH + fb + 4];
            float yv[8] = {h0.x, h0.y, h0.z, h0.w, h4.x, h4.y, h4.z, h4.w};
            v8s vh, vl;
            #pragma unroll
            for (int i = 0; i < 8; ++i) {
                const float y = fmaxf(yv[i] * lsc[kc][i] + lsh[kc][i], 0.f);
                bfraw hi, lo;
                f2bf2(y, hi, lo);
                vh[i] = (short)hi;
                vl[i] = (short)lo;
            }
            ah[kc] = vh; al[kc] = vl;
        }
        v4f c[2];
        #pragma unroll
        for (int ct = 0; ct < 2; ++ct) {
            v4f cc = (v4f){0.f, 0.f, 0.f, 0.f};
            #pragma unroll
            for (int kc = 0; kc < 4; ++kc) {
                cc = __builtin_amdgcn_mfma_f32_16x16x32_bf16(ah[kc], bhi[kc][ct], cc, 0, 0, 0);
                cc = __builtin_amdgcn_mfma_f32_16x16x32_bf16(ah[kc], blo[kc][ct], cc, 0, 0, 0);
                cc = __builtin_amdgcn_mfma_f32_16x16x32_bf16(al[kc], bhi[kc][ct], cc, 0, 0, 0);
            }
            c[ct] = cc;
        }
        #pragma unroll
        for (int ct = 0; ct < 2; ++ct) {
            #pragma unroll
            for (int r = 0; r < 4; ++r) {
                const int node = tb + kg * 4 + r;
                if (node < N) {
                    const size_t idx = (size_t)node * H + (cb + ct) * 16 + row;
                    const float v = x0[idx] + c[ct][r] + bcol[ct];
                    x0[idx] = v;
                    xh[idx] = f2h(fmaxf(v, 0.f));   // relu pre-folded, fp16
                }
            }
        }
    }
}

// ---------------- pooling + output ----------------
extern "C" __global__ void k_initout(const float* __restrict__ bout,
    float* __restrict__ out)
{
    if (threadIdx.x < NGRAPH) out[threadIdx.x] = bout[0];
}

// segment-sum pooling: batch is SORTED. Each wave owns a contiguous node slab;
// lane l accumulates feature l; flush (reduce+atomic) only at graph boundaries.
extern "C" __global__ void __launch_bounds__(256) k_pool(
    const float* __restrict__ x0, const int* __restrict__ batch,
    const float* __restrict__ Wout, float* __restrict__ out, int N)
{
    const int lane = threadIdx.x & 63;
    const int wpb = blockDim.x >> 6;
    const int gw = blockIdx.x * wpb + (threadIdx.x >> 6);
    const int nw = gridDim.x * wpb;
    const int per = (N + nw - 1) / nw;
    const int n0 = gw * per;
    int n1 = n0 + per; if (n1 > N) n1 = N;
    if (n0 >= N) return;
    const float wv = Wout[lane];
    int cur = batch[n0];
    float acc = 0.f;
    for (int n = n0; n < n1; ++n) {
        const int g = batch[n];
        if (g != cur) {
            float v = acc * wv;
            #pragma unroll
            for (int o = 32; o > 0; o >>= 1) v += __shfl_down(v, o);
            if (lane == 0) atomicAdd(&out[cur], v);
            cur = g;
            acc = 0.f;
        }
        acc += x0[(size_t)n * H + lane];
    }
    float v = acc * wv;
    #pragma unroll
    for (int o = 32; o > 0; o >>= 1) v += __shfl_down(v, o);
    if (lane == 0) atomicAdd(&out[cur], v);
}

// ---------------- host driver ----------------
extern "C" void kernel_launch(void* const* d_in, const int* in_sizes, int n_in,
                              void* d_out, int out_size, void* d_ws, size_t ws_size,
                              hipStream_t stream)
{
    const float* x     = (const float*)d_in[0];
    const int*   ei    = (const int*)d_in[1];   // int32 per harness conversion
    const int*   batch = (const int*)d_in[2];   // int32 per harness conversion
    const float* Win   = (const float*)d_in[3];
    const float* bin   = (const float*)d_in[4];
    const float* W1s   = (const float*)d_in[5];
    const float* b1s   = (const float*)d_in[6];
    const float* gam   = (const float*)d_in[7];
    const float* bet   = (const float*)d_in[8];
    const float* W2s   = (const float*)d_in[9];
    const float* b2s   = (const float*)d_in[10];
    const float* epss  = (const float*)d_in[11];
    const float* Wout  = (const float*)d_in[12];
    const float* bout  = (const float*)d_in[13];

    const int N = in_sizes[0] / CIN;
    const int E = in_sizes[1] / 2;
    const int L = in_sizes[11];
    const int* src = ei;
    const int* dst = ei + E;
    const int NB = (N + BNODE - 1) >> BSH;   // final buckets (<= MAXNB)

    // workspace layout
    char* ws = (char*)d_ws;
    size_t off = 0;
    auto take = [&](size_t bytes) {
        void* p = ws + off;
        off += (bytes + 255) & ~(size_t)255;
        return p;
    };
    float*    x0     = (float*)take((size_t)N * H * 4);
    bfraw*    xh     = (bfraw*)take((size_t)(N + 1) * H * 2);  // fp16, +1 zero row
    bfraw*    hprehi = (bfraw*)take((size_t)N * H * 2);
    bfraw*    hprelo = (bfraw*)take((size_t)N * H * 2);
    float*    h1     = (float*)take((size_t)N * TWOH * 4);
    unsigned* deg    = (unsigned*)take((size_t)N * 4);
    unsigned* indptr = (unsigned*)take((size_t)(N + 1) * 4);
    unsigned* cursor = (unsigned*)take((size_t)N * 4);
    int*      esrc   = (int*)take((size_t)(E + 4 * (N + 1)) * 4);  // padded
    unsigned* bsum   = (unsigned*)take(4096);
    double*   gsum   = (double*)take(TWOH * 8 * 2); // gsum + gsq contiguous
    double*   gsq    = gsum + TWOH;
    float*    scsh   = (float*)take(2 * TWOH * 4);
    bfraw*    W1hi   = (bfraw*)take((size_t)L * H * TWOH * 2);
    bfraw*    W1lo   = (bfraw*)take((size_t)L * H * TWOH * 2);
    bfraw*    W2hi   = (bfraw*)take((size_t)L * TWOH * H * 2);
    bfraw*    W2lo   = (bfraw*)take((size_t)L * TWOH * H * 2);
    unsigned* bcnt   = (unsigned*)take((size_t)NBLK_PART * NB * 4);
    unsigned* btmp   = (unsigned*)take((size_t)NBLK_PART * NB * BCAP * 4);
    int*      oflow  = (int*)take((size_t)OCAP * 2 * 4);
    unsigned* ocnt   = (unsigned*)take(256);
    (void)ws_size; (void)n_in; (void)out_size;

    hipMemsetAsync(deg, 0, (size_t)N * 4, stream);
    hipMemsetAsync(ocnt, 0, 4, stream);
    hipMemsetAsync(xh + (size_t)N * H, 0, H * 2, stream);  // sentinel zero row
    k_input_gemm<<<512, 256, 0, stream>>>(x, Win, bin, x0, xh, N);
    k_cvtw<<<256, 256, 0, stream>>>(W1s, W2s, W1hi, W1lo, W2hi, W2lo, L * H * TWOH);
    k_bucket<<<NBLK_PART, 256, 0, stream>>>(src, dst, bcnt, btmp, deg, oflow, ocnt, E, NB);
    k_bhist<<<NB, 256, 0, stream>>>(bcnt, btmp, deg, N, NB);
    const int nb = (N + 1023) / 1024;
    k_scan1<<<nb, 256, 0, stream>>>(deg, indptr, bsum, N);
    k_scan2<<<1, 64, 0, stream>>>(bsum, nb, indptr, N);
    k_scan3<<<nb, 256, 0, stream>>>(indptr, bsum, cursor, N);
    k_bscat<<<NB, 256, 0, stream>>>(bcnt, btmp, indptr, cursor, esrc, N, NB);
    k_over<<<32, 256, 0, stream>>>(oflow, ocnt, cursor, esrc);
    k_pad<<<512, 256, 0, stream>>>(cursor, indptr, esrc, N);

    for (int l = 0; l < L; ++l) {
        hipMemsetAsync(gsum, 0, TWOH * 8 * 2, stream);
        k_agg<<<4096, 256, 0, stream>>>(x0, xh, esrc, indptr, epss + l,
            hprehi, hprelo, N);
        k_gemm1<<<512, 256, 0, stream>>>(hprehi, hprelo,
            W1hi + (size_t)l * H * TWOH, W1lo + (size_t)l * H * TWOH,
            b1s + (size_t)l * TWOH, h1, gsum, gsq, N);
        k_bnfin<<<1, 128, 0, stream>>>(gsum, gsq, gam + (size_t)l * TWOH,
            bet + (size_t)l * TWOH, scsh, N);
        k_gemm2<<<512, 256, 0, stream>>>(h1, scsh,
            W2hi + (size_t)l * TWOH * H, W2lo + (size_t)l * TWOH * H,
            b2s + (size_t)l * H, x0, xh, N);
    }

    k_initout<<<1, 64, 0, stream>>>(bout, (float*)d_out);
    k_pool<<<512, 256, 0, stream>>>(x0, batch, Wout, (float*)d_out, N);
}

// Round 13
// 518.887 us; speedup vs baseline: 1.1549x; 1.1549x over previous
//
#include <hip/hip_runtime.h>
#include <hip/hip_fp16.h>

#define H 64
#define CIN 32
#define TWOH 128
#define NGRAPH 64

// bucketed CSR build
#define BSH 7
#define BNODE 128
#define NBLK_PART 256
#define BCAP 32
#define MAXNB 2048
#define OCAP 65536

typedef unsigned short bfraw;
typedef short v8s __attribute__((ext_vector_type(8)));
typedef float v4f __attribute__((ext_vector_type(4)));

__device__ __forceinline__ float bf2f(bfraw u) {
    return __uint_as_float(((unsigned)u) << 16);
}
__device__ __forceinline__ bfraw f2bf(float f) {
    unsigned u = __float_as_uint(f);
    unsigned r = (u + 0x7fffu + ((u >> 16) & 1u)) >> 16;  // RNE
    return (bfraw)r;
}
// split fp32 -> hi + lo bf16 (combined rel err ~2^-17)
__device__ __forceinline__ void f2bf2(float f, bfraw& hi, bfraw& lo) {
    hi = f2bf(f);
    lo = f2bf(f - bf2f(hi));
}
// fp16 raw bits (RNE)
__device__ __forceinline__ bfraw f2h(float f) {
    return __half_as_ushort(__float2half(f));
}
__device__ __forceinline__ __half2 u2h2(unsigned u) {
    union { unsigned u; __half2 h; } c; c.u = u; return c.h;
}

// ----- MFMA input GEMM: x0[N,64] = x[N,32] @ Win + bin; xh = fp16(relu(x0)) -----
extern "C" __global__ void __launch_bounds__(256) k_input_gemm(
    const float* __restrict__ x, const float* __restrict__ Win,
    const float* __restrict__ bin, float* __restrict__ x0,
    bfraw* __restrict__ xh, int N)
{
    const int lane = threadIdx.x & 63;
    const int row = lane & 15;
    const int kg  = lane >> 4;
    // B fragments: Win[32][64] split hi/lo, 1 k-chunk (K=32), 4 col-tiles
    v8s bhi[4], blo[4];
    #pragma unroll
    for (int ct = 0; ct < 4; ++ct) {
        v8s bh, bl;
        #pragma unroll
        for (int i = 0; i < 8; ++i) {
            const float w = Win[(kg * 8 + i) * H + ct * 16 + row];
            bfraw h, l; f2bf2(w, h, l);
            bh[i] = (short)h; bl[i] = (short)l;
        }
        bhi[ct] = bh; blo[ct] = bl;
    }
    float bcol[4];
    #pragma unroll
    for (int ct = 0; ct < 4; ++ct) bcol[ct] = bin[ct * 16 + row];

    const int wpb = blockDim.x >> 6;
    const int wid = blockIdx.x * wpb + (threadIdx.x >> 6);
    const int wstride = gridDim.x * wpb;
    const int tiles = (N + 15) >> 4;
    for (int t = wid; t < tiles; t += wstride) {
        const int tb = t << 4;
        int nA = tb + row; if (nA >= N) nA = N - 1;
        v8s ah, al;
        #pragma unroll
        for (int i = 0; i < 8; ++i) {
            const float v = x[(size_t)nA * CIN + kg * 8 + i];
            bfraw h, l; f2bf2(v, h, l);
            ah[i] = (short)h; al[i] = (short)l;
        }
        v4f c[4];
        #pragma unroll
        for (int ct = 0; ct < 4; ++ct) {
            v4f cc = (v4f){0.f, 0.f, 0.f, 0.f};
            cc = __builtin_amdgcn_mfma_f32_16x16x32_bf16(ah, bhi[ct], cc, 0, 0, 0);
            cc = __builtin_amdgcn_mfma_f32_16x16x32_bf16(ah, blo[ct], cc, 0, 0, 0);
            cc = __builtin_amdgcn_mfma_f32_16x16x32_bf16(al, bhi[ct], cc, 0, 0, 0);
            c[ct] = cc;
        }
        #pragma unroll
        for (int ct = 0; ct < 4; ++ct) {
            #pragma unroll
            for (int r = 0; r < 4; ++r) {
                const int node = tb + kg * 4 + r;
                if (node < N) {
                    const float v = c[ct][r] + bcol[ct];
                    const size_t idx = (size_t)node * H + ct * 16 + row;
                    x0[idx] = v;
                    xh[idx] = f2h(fmaxf(v, 0.f));   // relu pre-folded, fp16
                }
            }
        }
    }
}

// ---------------- weight conversion to split bf16 (all layers, once) ----------------
extern "C" __global__ void k_cvtw(const float* __restrict__ W1s,
    const float* __restrict__ W2s, bfraw* __restrict__ W1hi,
    bfraw* __restrict__ W1lo, bfraw* __restrict__ W2hi,
    bfraw* __restrict__ W2lo, int total)  // total = L*H*TWOH
{
    int i = blockIdx.x * blockDim.x + threadIdx.x;
    const int st = gridDim.x * blockDim.x;
    for (; i < total; i += st) {
        bfraw h, l;
        f2bf2(W1s[i], h, l); W1hi[i] = h; W1lo[i] = l;
        f2bf2(W2s[i], h, l); W2hi[i] = h; W2lo[i] = l;
    }
}

// ---------------- block-private bucket partition (pass A) ----------------
__device__ __forceinline__ void bput(int s, int d, unsigned* __restrict__ lcnt,
    unsigned* __restrict__ myTmp, unsigned* __restrict__ deg,
    int* __restrict__ oflow, unsigned* __restrict__ ocnt)
{
    const int b = d >> BSH;
    const unsigned pos = atomicAdd(&lcnt[b], 1u);   // LDS atomic
    if (pos < BCAP) {
        myTmp[b * BCAP + pos] = (unsigned)s | ((unsigned)(d & (BNODE - 1)) << 20);
    } else {
        const unsigned o = atomicAdd(ocnt, 1u);
        if (o < OCAP) {
            oflow[2 * o] = s; oflow[2 * o + 1] = d;
            atomicAdd(&deg[d], 1u);
        }
    }
}

extern "C" __global__ void __launch_bounds__(256) k_bucket(
    const int* __restrict__ src, const int* __restrict__ dst,
    unsigned* __restrict__ bcnt, unsigned* __restrict__ btmp,
    unsigned* __restrict__ deg, int* __restrict__ oflow,
    unsigned* __restrict__ ocnt, int E, int NBck)
{
    __shared__ unsigned lcnt[MAXNB];  // 8 KB (NBck <= 2048)
    for (int i = threadIdx.x; i < NBck; i += blockDim.x) lcnt[i] = 0u;
    __syncthreads();
    unsigned* __restrict__ myTmp = btmp + (size_t)blockIdx.x * NBck * BCAP;
    const int tid0 = blockIdx.x * blockDim.x + threadIdx.x;
    const int st = gridDim.x * blockDim.x;
    const int E4 = E >> 2;
    const int4* s4 = (const int4*)src;
    const int4* d4 = (const int4*)dst;
    for (int j = tid0; j < E4; j += st) {
        const int4 sv = s4[j];
        const int4 dv = d4[j];
        bput(sv.x, dv.x, lcnt, myTmp, deg, oflow, ocnt);
        bput(sv.y, dv.y, lcnt, myTmp, deg, oflow, ocnt);
        bput(sv.z, dv.z, lcnt, myTmp, deg, oflow, ocnt);
        bput(sv.w, dv.w, lcnt, myTmp, deg, oflow, ocnt);
    }
    for (int j = (E4 << 2) + tid0; j < E; j += st)
        bput(src[j], dst[j], lcnt, myTmp, deg, oflow, ocnt);
    __syncthreads();
    unsigned* __restrict__ myCnt = bcnt + (size_t)blockIdx.x * NBck;
    for (int i = threadIdx.x; i < NBck; i += blockDim.x) {
        const unsigned c = lcnt[i];
        myCnt[i] = (c < BCAP) ? c : BCAP;
    }
}

// ---------------- per-bucket degree histogram ----------------
extern "C" __global__ void __launch_bounds__(256) k_bhist(
    const unsigned* __restrict__ bcnt, const unsigned* __restrict__ btmp,
    unsigned* __restrict__ deg, int N, int NBck)
{
    __shared__ unsigned hist[BNODE];
    const int b = blockIdx.x;
    for (int i = threadIdx.x; i < BNODE; i += blockDim.x) hist[i] = 0u;
    __syncthreads();
    for (int blk = threadIdx.x; blk < NBLK_PART; blk += blockDim.x) {
        const unsigned cnt = bcnt[(size_t)blk * NBck + b];
        const unsigned* p = btmp + ((size_t)blk * NBck + b) * BCAP;
        for (unsigned j = 0; j < cnt; ++j)
            atomicAdd(&hist[p[j] >> 20], 1u);
    }
    __syncthreads();
    const int base = b << BSH;
    for (int i = threadIdx.x; i < BNODE; i += blockDim.x)
        if (base + i < N) {
            const unsigned h = hist[i];
            if (h) atomicAdd(&deg[base + i], h);
        }
}

extern "C" __global__ void k_scan1(const unsigned* __restrict__ deg,
    unsigned* __restrict__ indptr, unsigned* __restrict__ bsum, int N)
{
    __shared__ unsigned s[256];
    const int tid = threadIdx.x;
    const int base = blockIdx.x * 1024 + tid * 4;
    unsigned d[4];
    #pragma unroll
    for (int j = 0; j < 4; ++j)
        d[j] = (base + j < N) ? ((deg[base + j] + 7u) & ~7u) : 0u;  // pad to 8
    unsigned t = d[0] + d[1] + d[2] + d[3];
    s[tid] = t;
    __syncthreads();
    for (int o = 1; o < 256; o <<= 1) {
        unsigned v = (tid >= o) ? s[tid - o] : 0u;
        __syncthreads();
        s[tid] += v;
        __syncthreads();
    }
    unsigned run = (tid == 0) ? 0u : s[tid - 1];
    if (tid == 255) bsum[blockIdx.x] = s[255];
    #pragma unroll
    for (int j = 0; j < 4; ++j) {
        if (base + j < N) indptr[base + j] = run;
        run += d[j];
    }
}

extern "C" __global__ void k_scan2(unsigned* bsum, int nb,
    unsigned* __restrict__ indptr, int N)
{
    if (threadIdx.x == 0) {
        unsigned run = 0;
        for (int i = 0; i < nb; ++i) { unsigned v = bsum[i]; bsum[i] = run; run += v; }
        indptr[N] = run;  // total padded edges
    }
}

extern "C" __global__ void k_scan3(unsigned* __restrict__ indptr,
    const unsigned* __restrict__ bsum, unsigned* __restrict__ cursor, int N)
{
    const int base = blockIdx.x * 1024 + threadIdx.x * 4;
    const unsigned boff = bsum[blockIdx.x];
    #pragma unroll
    for (int j = 0; j < 4; ++j) {
        const int idx = base + j;
        if (idx < N) {
            const unsigned v = indptr[idx] + boff;
            indptr[idx] = v;
            cursor[idx] = v;
        }
    }
}

// ---------------- per-bucket scatter to final CSR (pass B) ----------------
extern "C" __global__ void __launch_bounds__(256) k_bscat(
    const unsigned* __restrict__ bcnt, const unsigned* __restrict__ btmp,
    const unsigned* __restrict__ indptr, unsigned* __restrict__ cursor,
    int* __restrict__ esrc, int N, int NBck)
{
    __shared__ unsigned lcur[BNODE];
    const int b = blockIdx.x;
    const int base = b << BSH;
    for (int i = threadIdx.x; i < BNODE; i += blockDim.x)
        lcur[i] = (base + i < N) ? indptr[base + i] : 0u;
    __syncthreads();
    for (int blk = threadIdx.x; blk < NBLK_PART; blk += blockDim.x) {
        const unsigned cnt = bcnt[(size_t)blk * NBck + b];
        const unsigned* p = btmp + ((size_t)blk * NBck + b) * BCAP;
        for (unsigned j = 0; j < cnt; ++j) {
            const unsigned e = p[j];
            const unsigned pos = atomicAdd(&lcur[e >> 20], 1u);
            esrc[pos] = (int)(e & 0xFFFFFu);
        }
    }
    __syncthreads();
    for (int i = threadIdx.x; i < BNODE; i += blockDim.x)
        if (base + i < N) cursor[base + i] = lcur[i];
}

// overflow edges (expected none) via global cursor
extern "C" __global__ void k_over(const int* __restrict__ oflow,
    const unsigned* __restrict__ ocnt, unsigned* __restrict__ cursor,
    int* __restrict__ esrc)
{
    unsigned n = *ocnt; if (n > OCAP) n = OCAP;
    int i = blockIdx.x * blockDim.x + threadIdx.x;
    const int st = gridDim.x * blockDim.x;
    for (; (unsigned)i < n; i += st) {
        const int s = oflow[2 * i], d = oflow[2 * i + 1];
        const unsigned pos = atomicAdd(&cursor[d], 1u);
        esrc[pos] = s;
    }
}

// fill padded slots with sentinel N (zero row)
extern "C" __global__ void k_pad(const unsigned* __restrict__ cursor,
    const unsigned* __restrict__ indptr, int* __restrict__ esrc, int N)
{
    int n = blockIdx.x * blockDim.x + threadIdx.x;
    const int st = gridDim.x * blockDim.x;
    for (; n < N; n += st) {
        const unsigned end = indptr[n + 1];
        for (unsigned p = cursor[n]; p < end; ++p) esrc[p] = N;
    }
}

// --- gather: hpre = (1+eps)*x0 + sum xh[src] (fp16, already relu'd); split bf16 ---
// degrees padded to 8: main 16-edge loop (4 loads), 8-edge step (2 loads).
extern "C" __global__ void __launch_bounds__(256) k_agg(
    const float* __restrict__ x0, const bfraw* __restrict__ xh,
    const int* __restrict__ esrc, const unsigned* __restrict__ indptr,
    const float* __restrict__ epsp, bfraw* __restrict__ hprehi,
    bfraw* __restrict__ hprelo, int N)
{
    const int lane = threadIdx.x & 63;
    const int sub = lane >> 4;          // 0..3 : which edge of the group
    const int fi = (lane & 15) << 2;    // feature base (4 features)
    const int wpb = blockDim.x >> 6;
    int w = blockIdx.x * wpb + (threadIdx.x >> 6);
    const int wstride = gridDim.x * wpb;
    const float ep = 1.f + epsp[0];
    for (int n = w; n < N; n += wstride) {
        const unsigned s0 = indptr[n];
        const unsigned s1 = indptr[n + 1];   // padded: (s1-s0)%8==0
        float a0 = 0.f, a1 = 0.f, a2 = 0.f, a3 = 0.f;
        unsigned e = s0;
        for (; e + 16 <= s1; e += 16) {
            int idx[4];
            #pragma unroll
            for (int j = 0; j < 4; ++j) idx[j] = esrc[e + 4 * j + sub];
            uint2 r[4];
            #pragma unroll
            for (int j = 0; j < 4; ++j)
                r[j] = *(const uint2*)&xh[(size_t)idx[j] * H + fi];
            const __half2 s01 = __hadd2(__hadd2(u2h2(r[0].x), u2h2(r[1].x)),
                                        __hadd2(u2h2(r[2].x), u2h2(r[3].x)));
            const __half2 s23 = __hadd2(__hadd2(u2h2(r[0].y), u2h2(r[1].y)),
                                        __hadd2(u2h2(r[2].y), u2h2(r[3].y)));
            const float2 f01 = __half22float2(s01);
            const float2 f23 = __half22float2(s23);
            a0 += f01.x; a1 += f01.y; a2 += f23.x; a3 += f23.y;
        }
        for (; e + 8 <= s1; e += 8) {
            const int i0 = esrc[e + sub];
            const int i1 = esrc[e + 4 + sub];
            const uint2 r0 = *(const uint2*)&xh[(size_t)i0 * H + fi];
            const uint2 r1 = *(const uint2*)&xh[(size_t)i1 * H + fi];
            const float2 f01 = __half22float2(__hadd2(u2h2(r0.x), u2h2(r1.x)));
            const float2 f23 = __half22float2(__hadd2(u2h2(r0.y), u2h2(r1.y)));
            a0 += f01.x; a1 += f01.y; a2 += f23.x; a3 += f23.y;
        }
        for (; e < s1; e += 4) {   // safety; unreachable with pad-8
            const int i0 = esrc[e + sub];
            const uint2 r = *(const uint2*)&xh[(size_t)i0 * H + fi];
            const float2 f01 = __half22float2(u2h2(r.x));
            const float2 f23 = __half22float2(u2h2(r.y));
            a0 += f01.x; a1 += f01.y; a2 += f23.x; a3 += f23.y;
        }
        #pragma unroll
        for (int o = 16; o < 64; o <<= 1) {
            a0 += __shfl_xor(a0, o);
            a1 += __shfl_xor(a1, o);
            a2 += __shfl_xor(a2, o);
            a3 += __shfl_xor(a3, o);
        }
        if (sub == 0) {
            const float4 self = *(const float4*)&x0[(size_t)n * H + fi];
            const float h0 = ep * self.x + a0;
            const float h1v = ep * self.y + a1;
            const float h2 = ep * self.z + a2;
            const float h3 = ep * self.w + a3;
            ushort4 ohi, olo;
            f2bf2(h0, ohi.x, olo.x);
            f2bf2(h1v, ohi.y, olo.y);
            f2bf2(h2, ohi.z, olo.z);
            f2bf2(h3, ohi.w, olo.w);
            *(ushort4*)&hprehi[(size_t)n * H + fi] = ohi;
            *(ushort4*)&hprelo[(size_t)n * H + fi] = olo;
        }
    }
}

// ------------- MFMA GEMM1 + BN stats: h1[N,128] = hpre @ W1 + b1 -------------
// split precision: C = Ahi*Whi + Ahi*Wlo + Alo*Whi. Each wave: half the cols.
extern "C" __global__ void __launch_bounds__(256) k_gemm1(
    const bfraw* __restrict__ hprehi, const bfraw* __restrict__ hprelo,
    const bfraw* __restrict__ W1hi, const bfraw* __restrict__ W1lo,
    const float* __restrict__ b1, float* __restrict__ h1,
    double* __restrict__ gsum, double* __restrict__ gsq, int N)
{
    __shared__ float ss[TWOH], sq[TWOH];
    if (threadIdx.x < TWOH) { ss[threadIdx.x] = 0.f; sq[threadIdx.x] = 0.f; }
    __syncthreads();
    const int lane = threadIdx.x & 63;
    const int row = lane & 15;   // A row / B col / D col
    const int kg  = lane >> 4;   // k-group
    const int wpb = blockDim.x >> 6;
    const int wid = blockIdx.x * wpb + (threadIdx.x >> 6);
    const int wstride = gridDim.x * wpb;
    const int half = wid & 1;          // which 64 of the 128 cols
    const int cb = half * 4;           // col-tile base
    // preload B fragments: 2 k-chunks x 4 col-tiles, hi+lo
    v8s bhi[2][4], blo[2][4];
    #pragma unroll
    for (int kc = 0; kc < 2; ++kc)
        #pragma unroll
        for (int ct = 0; ct < 4; ++ct) {
            v8s bh, bl;
            #pragma unroll
            for (int i = 0; i < 8; ++i) {
                const int idx = (kc * 32 + kg * 8 + i) * TWOH + (cb + ct) * 16 + row;
                bh[i] = (short)W1hi[idx];
                bl[i] = (short)W1lo[idx];
            }
            bhi[kc][ct] = bh; blo[kc][ct] = bl;
        }
    float bcol[4];
    #pragma unroll
    for (int ct = 0; ct < 4; ++ct) bcol[ct] = b1[(cb + ct) * 16 + row];

    const int tiles = (N + 15) >> 4;
    const int tstride = wstride >> 1;
    float sacc[4], qacc[4];
    #pragma unroll
    for (int ct = 0; ct < 4; ++ct) { sacc[ct] = 0.f; qacc[ct] = 0.f; }

    for (int t = wid >> 1; t < tiles; t += tstride) {
        const int tb = t << 4;
        int nA = tb + row; if (nA >= N) nA = N - 1;
        const v8s a0h = *(const v8s*)&hprehi[(size_t)nA * H + kg * 8];
        const v8s a1h = *(const v8s*)&hprehi[(size_t)nA * H + 32 + kg * 8];
        const v8s a0l = *(const v8s*)&hprelo[(size_t)nA * H + kg * 8];
        const v8s a1l = *(const v8s*)&hprelo[(size_t)nA * H + 32 + kg * 8];
        v4f c[4];
        #pragma unroll
        for (int ct = 0; ct < 4; ++ct) {
            v4f cc = (v4f){0.f, 0.f, 0.f, 0.f};
            cc = __builtin_amdgcn_mfma_f32_16x16x32_bf16(a0h, bhi[0][ct], cc, 0, 0, 0);
            cc = __builtin_amdgcn_mfma_f32_16x16x32_bf16(a1h, bhi[1][ct], cc, 0, 0, 0);
            cc = __builtin_amdgcn_mfma_f32_16x16x32_bf16(a0h, blo[0][ct], cc, 0, 0, 0);
            cc = __builtin_amdgcn_mfma_f32_16x16x32_bf16(a1h, blo[1][ct], cc, 0, 0, 0);
            cc = __builtin_amdgcn_mfma_f32_16x16x32_bf16(a0l, bhi[0][ct], cc, 0, 0, 0);
            cc = __builtin_amdgcn_mfma_f32_16x16x32_bf16(a1l, bhi[1][ct], cc, 0, 0, 0);
            c[ct] = cc;
        }
        #pragma unroll
        for (int ct = 0; ct < 4; ++ct) {
            #pragma unroll
            for (int r = 0; r < 4; ++r) {
                const int node = tb + kg * 4 + r;  // D row
                if (node < N) {
                    const float v = c[ct][r] + bcol[ct];
                    h1[(size_t)node * TWOH + (cb + ct) * 16 + row] = v;
                    sacc[ct] += v;
                    qacc[ct] += v * v;
                }
            }
        }
    }
    #pragma unroll
    for (int ct = 0; ct < 4; ++ct) {
        float s = sacc[ct];
        s += __shfl_xor(s, 16); s += __shfl_xor(s, 32);
        float q = qacc[ct];
        q += __shfl_xor(q, 16); q += __shfl_xor(q, 32);
        if (kg == 0) {
            atomicAdd(&ss[(cb + ct) * 16 + row], s);
            atomicAdd(&sq[(cb + ct) * 16 + row], q);
        }
    }
    __syncthreads();
    if (threadIdx.x < TWOH) {
        atomicAdd(&gsum[threadIdx.x], (double)ss[threadIdx.x]);
        atomicAdd(&gsq[threadIdx.x], (double)sq[threadIdx.x]);
    }
}

// ---------------- BN finalize: scale/shift ----------------
extern "C" __global__ void k_bnfin(const double* __restrict__ gsum,
    const double* __restrict__ gsq, const float* __restrict__ gamma,
    const float* __restrict__ beta, float* __restrict__ scsh, int N)
{
    const int j = threadIdx.x;
    if (j < TWOH) {
        const double mu = gsum[j] / N;
        const double var = gsq[j] / N - mu * mu;
        const float sc = gamma[j] * rsqrtf(fmaxf((float)var, 0.f) + 1e-5f);
        scsh[j] = sc;
        scsh[TWOH + j] = beta[j] - (float)mu * sc;
    }
}

// --- MFMA GEMM2 + fused BN/ReLU + residual: x0 += relu(h1*sc+sh) @ W2 + b2 ---
extern "C" __global__ void __launch_bounds__(256) k_gemm2(
    const float* __restrict__ h1, const float* __restrict__ scsh,
    const bfraw* __restrict__ W2hi, const bfraw* __restrict__ W2lo,
    const float* __restrict__ b2, float* __restrict__ x0,
    bfraw* __restrict__ xh, int N)
{
    __shared__ float scl[TWOH], shl[TWOH];  // 1 KB
    for (int i = threadIdx.x; i < TWOH; i += blockDim.x) {
        scl[i] = scsh[i];
        shl[i] = scsh[TWOH + i];
    }
    __syncthreads();
    const int lane = threadIdx.x & 63;
    const int row = lane & 15;
    const int kg  = lane >> 4;
    const int wpb = blockDim.x >> 6;
    const int wid = blockIdx.x * wpb + (threadIdx.x >> 6);
    const int wstride = gridDim.x * wpb;
    const int half = wid & 1;       // which 32 of the 64 cols
    const int cb = half * 2;        // col-tile base
    // preload B fragments: 4 k-chunks x 2 col-tiles, hi+lo
    v8s bhi[4][2], blo[4][2];
    #pragma unroll
    for (int kc = 0; kc < 4; ++kc)
        #pragma unroll
        for (int ct = 0; ct < 2; ++ct) {
            v8s bh, bl;
            #pragma unroll
            for (int i = 0; i < 8; ++i) {
                const int idx = (kc * 32 + kg * 8 + i) * H + (cb + ct) * 16 + row;
                bh[i] = (short)W2hi[idx];
                bl[i] = (short)W2lo[idx];
            }
            bhi[kc][ct] = bh; blo[kc][ct] = bl;
        }
    float bcol[2];
    #pragma unroll
    for (int ct = 0; ct < 2; ++ct) bcol[ct] = b2[(cb + ct) * 16 + row];
    // per-lane BN constants for this lane's 32 features (8 per k-chunk)
    float lsc[4][8], lsh[4][8];
    #pragma unroll
    for (int kc = 0; kc < 4; ++kc) {
        const int fb = kc * 32 + kg * 8;
        #pragma unroll
        for (int i = 0; i < 8; ++i) { lsc[kc][i] = scl[fb + i]; lsh[kc][i] = shl[fb + i]; }
    }

    const int tiles = (N + 15) >> 4;
    const int tstride = wstride >> 1;

    for (int t = wid >> 1; t < tiles; t += tstride) {
        const int tb = t << 4;
        int nA = tb + row; if (nA >= N) nA = N - 1;
        v8s ah[4], al[4];
        #pragma unroll
        for (int kc = 0; kc < 4; ++kc) {
            const int fb = kc * 32 + kg * 8;
            const float4 h0 = *(const float4*)&h1[(size_t)nA * TWOH + fb];
            const float4 h4 = *(const float4*)&h1[(size_t)nA * TWOH + fb + 4];
            float yv[8] = {h0.x, h0.y, h0.z, h0.w, h4.x, h4.y, h4.z, h4.w};
            v8s vh, vl;
            #pragma unroll
            for (int i = 0; i < 8; ++i) {
                const float y = fmaxf(yv[i] * lsc[kc][i] + lsh[kc][i], 0.f);
                bfraw hi, lo;
                f2bf2(y, hi, lo);
                vh[i] = (short)hi;
                vl[i] = (short)lo;
            }
            ah[kc] = vh; al[kc] = vl;
        }
        v4f c[2];
        #pragma unroll
        for (int ct = 0; ct < 2; ++ct) {
            v4f cc = (v4f){0.f, 0.f, 0.f, 0.f};
            #pragma unroll
            for (int kc = 0; kc < 4; ++kc) {
                cc = __builtin_amdgcn_mfma_f32_16x16x32_bf16(ah[kc], bhi[kc][ct], cc, 0, 0, 0);
                cc = __builtin_amdgcn_mfma_f32_16x16x32_bf16(ah[kc], blo[kc][ct], cc, 0, 0, 0);
                cc = __builtin_amdgcn_mfma_f32_16x16x32_bf16(al[kc], bhi[kc][ct], cc, 0, 0, 0);
            }
            c[ct] = cc;
        }
        #pragma unroll
        for (int ct = 0; ct < 2; ++ct) {
            #pragma unroll
            for (int r = 0; r < 4; ++r) {
                const int node = tb + kg * 4 + r;
                if (node < N) {
                    const size_t idx = (size_t)node * H + (cb + ct) * 16 + row;
                    const float v = x0[idx] + c[ct][r] + bcol[ct];
                    x0[idx] = v;
                    xh[idx] = f2h(fmaxf(v, 0.f));   // relu pre-folded, fp16
                }
            }
        }
    }
}

// ---------------- pooling + output ----------------
extern "C" __global__ void k_initout(const float* __restrict__ bout,
    float* __restrict__ out)
{
    if (threadIdx.x < NGRAPH) out[threadIdx.x] = bout[0];
}

// segment-sum pooling: batch is SORTED. Each wave owns a contiguous node slab;
// lane l accumulates feature l; flush (reduce+atomic) only at graph boundaries.
extern "C" __global__ void __launch_bounds__(256) k_pool(
    const float* __restrict__ x0, const int* __restrict__ batch,
    const float* __restrict__ Wout, float* __restrict__ out, int N)
{
    const int lane = threadIdx.x & 63;
    const int wpb = blockDim.x >> 6;
    const int gw = blockIdx.x * wpb + (threadIdx.x >> 6);
    const int nw = gridDim.x * wpb;
    const int per = (N + nw - 1) / nw;
    const int n0 = gw * per;
    int n1 = n0 + per; if (n1 > N) n1 = N;
    if (n0 >= N) return;
    const float wv = Wout[lane];
    int cur = batch[n0];
    float acc = 0.f;
    for (int n = n0; n < n1; ++n) {
        const int g = batch[n];
        if (g != cur) {
            float v = acc * wv;
            #pragma unroll
            for (int o = 32; o > 0; o >>= 1) v += __shfl_down(v, o);
            if (lane == 0) atomicAdd(&out[cur], v);
            cur = g;
            acc = 0.f;
        }
        acc += x0[(size_t)n * H + lane];
    }
    float v = acc * wv;
    #pragma unroll
    for (int o = 32; o > 0; o >>= 1) v += __shfl_down(v, o);
    if (lane == 0) atomicAdd(&out[cur], v);
}

// ---------------- host driver ----------------
extern "C" void kernel_launch(void* const* d_in, const int* in_sizes, int n_in,
                              void* d_out, int out_size, void* d_ws, size_t ws_size,
                              hipStream_t stream)
{
    const float* x     = (const float*)d_in[0];
    const int*   ei    = (const int*)d_in[1];   // int32 per harness conversion
    const int*   batch = (const int*)d_in[2];   // int32 per harness conversion
    const float* Win   = (const float*)d_in[3];
    const float* bin   = (const float*)d_in[4];
    const float* W1s   = (const float*)d_in[5];
    const float* b1s   = (const float*)d_in[6];
    const float* gam   = (const float*)d_in[7];
    const float* bet   = (const float*)d_in[8];
    const float* W2s   = (const float*)d_in[9];
    const float* b2s   = (const float*)d_in[10];
    const float* epss  = (const float*)d_in[11];
    const float* Wout  = (const float*)d_in[12];
    const float* bout  = (const float*)d_in[13];

    const int N = in_sizes[0] / CIN;
    const int E = in_sizes[1] / 2;
    const int L = in_sizes[11];
    const int* src = ei;
    const int* dst = ei + E;
    const int NB = (N + BNODE - 1) >> BSH;   // final buckets (<= MAXNB)

    // workspace layout
    char* ws = (char*)d_ws;
    size_t off = 0;
    auto take = [&](size_t bytes) {
        void* p = ws + off;
        off += (bytes + 255) & ~(size_t)255;
        return p;
    };
    float*    x0     = (float*)take((size_t)N * H * 4);
    bfraw*    xh     = (bfraw*)take((size_t)(N + 1) * H * 2);  // fp16, +1 zero row
    bfraw*    hprehi = (bfraw*)take((size_t)N * H * 2);
    bfraw*    hprelo = (bfraw*)take((size_t)N * H * 2);
    float*    h1     = (float*)take((size_t)N * TWOH * 4);
    unsigned* deg    = (unsigned*)take((size_t)N * 4);
    unsigned* indptr = (unsigned*)take((size_t)(N + 1) * 4);
    unsigned* cursor = (unsigned*)take((size_t)N * 4);
    int*      esrc   = (int*)take((size_t)(E + 8 * (N + 1)) * 4);  // padded to 8
    unsigned* bsum   = (unsigned*)take(4096);
    double*   gsum   = (double*)take(TWOH * 8 * 2); // gsum + gsq contiguous
    double*   gsq    = gsum + TWOH;
    float*    scsh   = (float*)take(2 * TWOH * 4);
    bfraw*    W1hi   = (bfraw*)take((size_t)L * H * TWOH * 2);
    bfraw*    W1lo   = (bfraw*)take((size_t)L * H * TWOH * 2);
    bfraw*    W2hi   = (bfraw*)take((size_t)L * TWOH * H * 2);
    bfraw*    W2lo   = (bfraw*)take((size_t)L * TWOH * H * 2);
    unsigned* bcnt   = (unsigned*)take((size_t)NBLK_PART * NB * 4);
    unsigned* btmp   = (unsigned*)take((size_t)NBLK_PART * NB * BCAP * 4);
    int*      oflow  = (int*)take((size_t)OCAP * 2 * 4);
    unsigned* ocnt   = (unsigned*)take(256);
    (void)ws_size; (void)n_in; (void)out_size;

    hipMemsetAsync(deg, 0, (size_t)N * 4, stream);
    hipMemsetAsync(ocnt, 0, 4, stream);
    hipMemsetAsync(xh + (size_t)N * H, 0, H * 2, stream);  // sentinel zero row
    k_input_gemm<<<512, 256, 0, stream>>>(x, Win, bin, x0, xh, N);
    k_cvtw<<<256, 256, 0, stream>>>(W1s, W2s, W1hi, W1lo, W2hi, W2lo, L * H * TWOH);
    k_bucket<<<NBLK_PART, 256, 0, stream>>>(src, dst, bcnt, btmp, deg, oflow, ocnt, E, NB);
    k_bhist<<<NB, 256, 0, stream>>>(bcnt, btmp, deg, N, NB);
    const int nb = (N + 1023) / 1024;
    k_scan1<<<nb, 256, 0, stream>>>(deg, indptr, bsum, N);
    k_scan2<<<1, 64, 0, stream>>>(bsum, nb, indptr, N);
    k_scan3<<<nb, 256, 0, stream>>>(indptr, bsum, cursor, N);
    k_bscat<<<NB, 256, 0, stream>>>(bcnt, btmp, indptr, cursor, esrc, N, NB);
    k_over<<<32, 256, 0, stream>>>(oflow, ocnt, cursor, esrc);
    k_pad<<<512, 256, 0, stream>>>(cursor, indptr, esrc, N);

    for (int l = 0; l < L; ++l) {
        hipMemsetAsync(gsum, 0, TWOH * 8 * 2, stream);
        k_agg<<<4096, 256, 0, stream>>>(x0, xh, esrc, indptr, epss + l,
            hprehi, hprelo, N);
        k_gemm1<<<512, 256, 0, stream>>>(hprehi, hprelo,
            W1hi + (size_t)l * H * TWOH, W1lo + (size_t)l * H * TWOH,
            b1s + (size_t)l * TWOH, h1, gsum, gsq, N);
        k_bnfin<<<1, 128, 0, stream>>>(gsum, gsq, gam + (size_t)l * TWOH,
            bet + (size_t)l * TWOH, scsh, N);
        k_gemm2<<<512, 256, 0, stream>>>(h1, scsh,
            W2hi + (size_t)l * TWOH * H, W2lo + (size_t)l * TWOH * H,
            b2s + (size_t)l * H, x0, xh, N);
    }

    k_initout<<<1, 64, 0, stream>>>(bout, (float*)d_out);
    k_pool<<<512, 256, 0, stream>>>(x0, batch, Wout, (float*)d_out, N);
}

// Round 14
// 469.205 us; speedup vs baseline: 1.2772x; 1.1059x over previous
//
#include <hip/hip_runtime.h>
#include <hip/hip_fp16.h>

#define H 64
#define CIN 32
#define TWOH 128
#define NGRAPH 64

// bucketed CSR build
#define BSH 7
#define BNODE 128
#define NBLK_PART 256
#define BCAP 32
#define MAXNB 2048
#define OCAP 65536

typedef unsigned short bfraw;
typedef _Float16 v8h __attribute__((ext_vector_type(8)));
typedef unsigned short v8u __attribute__((ext_vector_type(8)));
typedef float v4f __attribute__((ext_vector_type(4)));

union h8cast { v8u u; v8h h; uint4 q; };

// fp16 raw bits (RNE)
__device__ __forceinline__ bfraw f2h(float f) {
    return __half_as_ushort(__float2half(f));
}
__device__ __forceinline__ float h2f(bfraw u) {
    return __half2float(__ushort_as_half(u));
}
__device__ __forceinline__ __half2 u2h2(unsigned u) {
    union { unsigned u; __half2 h; } c; c.u = u; return c.h;
}
// split fp32 -> hi + lo fp16 (combined rel err ~2^-22)
__device__ __forceinline__ void f2h2(float f, _Float16& hi, _Float16& lo) {
    hi = (_Float16)f;
    lo = (_Float16)(f - (float)hi);
}

// ----- MFMA input GEMM: x0[N,64] = x[N,32] @ Win + bin; xh = fp16(relu(x0)) -----
extern "C" __global__ void __launch_bounds__(256) k_input_gemm(
    const float* __restrict__ x, const float* __restrict__ Win,
    const float* __restrict__ bin, float* __restrict__ x0,
    bfraw* __restrict__ xh, int N)
{
    const int lane = threadIdx.x & 63;
    const int row = lane & 15;
    const int kg  = lane >> 4;
    // B fragments: Win[32][64] split fp16 hi/lo, 1 k-chunk (K=32), 4 col-tiles
    v8h bhi[4], blo[4];
    #pragma unroll
    for (int ct = 0; ct < 4; ++ct) {
        v8h bh, bl;
        #pragma unroll
        for (int i = 0; i < 8; ++i) {
            const float w = Win[(kg * 8 + i) * H + ct * 16 + row];
            _Float16 h, l; f2h2(w, h, l);
            bh[i] = h; bl[i] = l;
        }
        bhi[ct] = bh; blo[ct] = bl;
    }
    float bcol[4];
    #pragma unroll
    for (int ct = 0; ct < 4; ++ct) bcol[ct] = bin[ct * 16 + row];

    const int wpb = blockDim.x >> 6;
    const int wid = blockIdx.x * wpb + (threadIdx.x >> 6);
    const int wstride = gridDim.x * wpb;
    const int tiles = (N + 15) >> 4;
    for (int t = wid; t < tiles; t += wstride) {
        const int tb = t << 4;
        int nA = tb + row; if (nA >= N) nA = N - 1;
        v8h a;
        #pragma unroll
        for (int i = 0; i < 8; ++i)
            a[i] = (_Float16)x[(size_t)nA * CIN + kg * 8 + i];
        v4f c[4];
        #pragma unroll
        for (int ct = 0; ct < 4; ++ct) {
            v4f cc = (v4f){0.f, 0.f, 0.f, 0.f};
            cc = __builtin_amdgcn_mfma_f32_16x16x32_f16(a, bhi[ct], cc, 0, 0, 0);
            cc = __builtin_amdgcn_mfma_f32_16x16x32_f16(a, blo[ct], cc, 0, 0, 0);
            c[ct] = cc;
        }
        #pragma unroll
        for (int ct = 0; ct < 4; ++ct) {
            #pragma unroll
            for (int r = 0; r < 4; ++r) {
                const int node = tb + kg * 4 + r;
                if (node < N) {
                    const float v = c[ct][r] + bcol[ct];
                    const size_t idx = (size_t)node * H + ct * 16 + row;
                    x0[idx] = v;
                    xh[idx] = f2h(fmaxf(v, 0.f));   // relu pre-folded, fp16
                }
            }
        }
    }
}

// ------------- weight conversion to split fp16 (all layers, once) -------------
extern "C" __global__ void k_cvtw(const float* __restrict__ W1s,
    const float* __restrict__ W2s, bfraw* __restrict__ W1hi,
    bfraw* __restrict__ W1lo, bfraw* __restrict__ W2hi,
    bfraw* __restrict__ W2lo, int total)  // total = L*H*TWOH
{
    int i = blockIdx.x * blockDim.x + threadIdx.x;
    const int st = gridDim.x * blockDim.x;
    for (; i < total; i += st) {
        {
            const float w = W1s[i];
            const bfraw hb = f2h(w);
            W1hi[i] = hb;
            W1lo[i] = f2h(w - h2f(hb));
        }
        {
            const float w = W2s[i];
            const bfraw hb = f2h(w);
            W2hi[i] = hb;
            W2lo[i] = f2h(w - h2f(hb));
        }
    }
}

// ---------------- block-private bucket partition (pass A) ----------------
__device__ __forceinline__ void bput(int s, int d, unsigned* __restrict__ lcnt,
    unsigned* __restrict__ myTmp, unsigned* __restrict__ deg,
    int* __restrict__ oflow, unsigned* __restrict__ ocnt)
{
    const int b = d >> BSH;
    const unsigned pos = atomicAdd(&lcnt[b], 1u);   // LDS atomic
    if (pos < BCAP) {
        myTmp[b * BCAP + pos] = (unsigned)s | ((unsigned)(d & (BNODE - 1)) << 20);
    } else {
        const unsigned o = atomicAdd(ocnt, 1u);
        if (o < OCAP) {
            oflow[2 * o] = s; oflow[2 * o + 1] = d;
            atomicAdd(&deg[d], 1u);
        }
    }
}

extern "C" __global__ void __launch_bounds__(256) k_bucket(
    const int* __restrict__ src, const int* __restrict__ dst,
    unsigned* __restrict__ bcnt, unsigned* __restrict__ btmp,
    unsigned* __restrict__ deg, int* __restrict__ oflow,
    unsigned* __restrict__ ocnt, int E, int NBck)
{
    __shared__ unsigned lcnt[MAXNB];  // 8 KB (NBck <= 2048)
    for (int i = threadIdx.x; i < NBck; i += blockDim.x) lcnt[i] = 0u;
    __syncthreads();
    unsigned* __restrict__ myTmp = btmp + (size_t)blockIdx.x * NBck * BCAP;
    const int tid0 = blockIdx.x * blockDim.x + threadIdx.x;
    const int st = gridDim.x * blockDim.x;
    const int E4 = E >> 2;
    const int4* s4 = (const int4*)src;
    const int4* d4 = (const int4*)dst;
    for (int j = tid0; j < E4; j += st) {
        const int4 sv = s4[j];
        const int4 dv = d4[j];
        bput(sv.x, dv.x, lcnt, myTmp, deg, oflow, ocnt);
        bput(sv.y, dv.y, lcnt, myTmp, deg, oflow, ocnt);
        bput(sv.z, dv.z, lcnt, myTmp, deg, oflow, ocnt);
        bput(sv.w, dv.w, lcnt, myTmp, deg, oflow, ocnt);
    }
    for (int j = (E4 << 2) + tid0; j < E; j += st)
        bput(src[j], dst[j], lcnt, myTmp, deg, oflow, ocnt);
    __syncthreads();
    unsigned* __restrict__ myCnt = bcnt + (size_t)blockIdx.x * NBck;
    for (int i = threadIdx.x; i < NBck; i += blockDim.x) {
        const unsigned c = lcnt[i];
        myCnt[i] = (c < BCAP) ? c : BCAP;
    }
}

// ---------------- per-bucket degree histogram ----------------
extern "C" __global__ void __launch_bounds__(256) k_bhist(
    const unsigned* __restrict__ bcnt, const unsigned* __restrict__ btmp,
    unsigned* __restrict__ deg, int N, int NBck)
{
    __shared__ unsigned hist[BNODE];
    const int b = blockIdx.x;
    for (int i = threadIdx.x; i < BNODE; i += blockDim.x) hist[i] = 0u;
    __syncthreads();
    for (int blk = threadIdx.x; blk < NBLK_PART; blk += blockDim.x) {
        const unsigned cnt = bcnt[(size_t)blk * NBck + b];
        const unsigned* p = btmp + ((size_t)blk * NBck + b) * BCAP;
        for (unsigned j = 0; j < cnt; ++j)
            atomicAdd(&hist[p[j] >> 20], 1u);
    }
    __syncthreads();
    const int base = b << BSH;
    for (int i = threadIdx.x; i < BNODE; i += blockDim.x)
        if (base + i < N) {
            const unsigned h = hist[i];
            if (h) atomicAdd(&deg[base + i], h);
        }
}

extern "C" __global__ void k_scan1(const unsigned* __restrict__ deg,
    unsigned* __restrict__ indptr, unsigned* __restrict__ bsum, int N)
{
    __shared__ unsigned s[256];
    const int tid = threadIdx.x;
    const int base = blockIdx.x * 1024 + tid * 4;
    unsigned d[4];
    #pragma unroll
    for (int j = 0; j < 4; ++j)
        d[j] = (base + j < N) ? ((deg[base + j] + 7u) & ~7u) : 0u;  // pad to 8
    unsigned t = d[0] + d[1] + d[2] + d[3];
    s[tid] = t;
    __syncthreads();
    for (int o = 1; o < 256; o <<= 1) {
        unsigned v = (tid >= o) ? s[tid - o] : 0u;
        __syncthreads();
        s[tid] += v;
        __syncthreads();
    }
    unsigned run = (tid == 0) ? 0u : s[tid - 1];
    if (tid == 255) bsum[blockIdx.x] = s[255];
    #pragma unroll
    for (int j = 0; j < 4; ++j) {
        if (base + j < N) indptr[base + j] = run;
        run += d[j];
    }
}

extern "C" __global__ void k_scan2(unsigned* bsum, int nb,
    unsigned* __restrict__ indptr, int N)
{
    if (threadIdx.x == 0) {
        unsigned run = 0;
        for (int i = 0; i < nb; ++i) { unsigned v = bsum[i]; bsum[i] = run; run += v; }
        indptr[N] = run;  // total padded edges
    }
}

extern "C" __global__ void k_scan3(unsigned* __restrict__ indptr,
    const unsigned* __restrict__ bsum, unsigned* __restrict__ cursor, int N)
{
    const int base = blockIdx.x * 1024 + threadIdx.x * 4;
    const unsigned boff = bsum[blockIdx.x];
    #pragma unroll
    for (int j = 0; j < 4; ++j) {
        const int idx = base + j;
        if (idx < N) {
            const unsigned v = indptr[idx] + boff;
            indptr[idx] = v;
            cursor[idx] = v;
        }
    }
}

// ---------------- per-bucket scatter to final CSR (pass B) ----------------
extern "C" __global__ void __launch_bounds__(256) k_bscat(
    const unsigned* __restrict__ bcnt, const unsigned* __restrict__ btmp,
    const unsigned* __restrict__ indptr, unsigned* __restrict__ cursor,
    int* __restrict__ esrc, int N, int NBck)
{
    __shared__ unsigned lcur[BNODE];
    const int b = blockIdx.x;
    const int base = b << BSH;
    for (int i = threadIdx.x; i < BNODE; i += blockDim.x)
        lcur[i] = (base + i < N) ? indptr[base + i] : 0u;
    __syncthreads();
    for (int blk = threadIdx.x; blk < NBLK_PART; blk += blockDim.x) {
        const unsigned cnt = bcnt[(size_t)blk * NBck + b];
        const unsigned* p = btmp + ((size_t)blk * NBck + b) * BCAP;
        for (unsigned j = 0; j < cnt; ++j) {
            const unsigned e = p[j];
            const unsigned pos = atomicAdd(&lcur[e >> 20], 1u);
            esrc[pos] = (int)(e & 0xFFFFFu);
        }
    }
    __syncthreads();
    for (int i = threadIdx.x; i < BNODE; i += blockDim.x)
        if (base + i < N) cursor[base + i] = lcur[i];
}

// overflow edges (expected none) via global cursor
extern "C" __global__ void k_over(const int* __restrict__ oflow,
    const unsigned* __restrict__ ocnt, unsigned* __restrict__ cursor,
    int* __restrict__ esrc)
{
    unsigned n = *ocnt; if (n > OCAP) n = OCAP;
    int i = blockIdx.x * blockDim.x + threadIdx.x;
    const int st = gridDim.x * blockDim.x;
    for (; (unsigned)i < n; i += st) {
        const int s = oflow[2 * i], d = oflow[2 * i + 1];
        const unsigned pos = atomicAdd(&cursor[d], 1u);
        esrc[pos] = s;
    }
}

// fill padded slots with sentinel N (zero row)
extern "C" __global__ void k_pad(const unsigned* __restrict__ cursor,
    const unsigned* __restrict__ indptr, int* __restrict__ esrc, int N)
{
    int n = blockIdx.x * blockDim.x + threadIdx.x;
    const int st = gridDim.x * blockDim.x;
    for (; n < N; n += st) {
        const unsigned end = indptr[n + 1];
        for (unsigned p = cursor[n]; p < end; ++p) esrc[p] = N;
    }
}

// --- gather: hpreh = fp16((1+eps)*x0 + sum xh[src]); degrees padded to 8 ---
extern "C" __global__ void __launch_bounds__(256) k_agg(
    const float* __restrict__ x0, const bfraw* __restrict__ xh,
    const int* __restrict__ esrc, const unsigned* __restrict__ indptr,
    const float* __restrict__ epsp, bfraw* __restrict__ hpreh, int N)
{
    const int lane = threadIdx.x & 63;
    const int sub = lane >> 4;          // 0..3 : which edge of the group
    const int fi = (lane & 15) << 2;    // feature base (4 features)
    const int wpb = blockDim.x >> 6;
    int w = blockIdx.x * wpb + (threadIdx.x >> 6);
    const int wstride = gridDim.x * wpb;
    const float ep = 1.f + epsp[0];
    for (int n = w; n < N; n += wstride) {
        const unsigned s0 = indptr[n];
        const unsigned s1 = indptr[n + 1];   // padded: (s1-s0)%8==0
        float a0 = 0.f, a1 = 0.f, a2 = 0.f, a3 = 0.f;
        unsigned e = s0;
        for (; e + 16 <= s1; e += 16) {
            int idx[4];
            #pragma unroll
            for (int j = 0; j < 4; ++j) idx[j] = esrc[e + 4 * j + sub];
            uint2 r[4];
            #pragma unroll
            for (int j = 0; j < 4; ++j)
                r[j] = *(const uint2*)&xh[(size_t)idx[j] * H + fi];
            const __half2 s01 = __hadd2(__hadd2(u2h2(r[0].x), u2h2(r[1].x)),
                                        __hadd2(u2h2(r[2].x), u2h2(r[3].x)));
            const __half2 s23 = __hadd2(__hadd2(u2h2(r[0].y), u2h2(r[1].y)),
                                        __hadd2(u2h2(r[2].y), u2h2(r[3].y)));
            const float2 f01 = __half22float2(s01);
            const float2 f23 = __half22float2(s23);
            a0 += f01.x; a1 += f01.y; a2 += f23.x; a3 += f23.y;
        }
        for (; e + 8 <= s1; e += 8) {
            const int i0 = esrc[e + sub];
            const int i1 = esrc[e + 4 + sub];
            const uint2 r0 = *(const uint2*)&xh[(size_t)i0 * H + fi];
            const uint2 r1 = *(const uint2*)&xh[(size_t)i1 * H + fi];
            const float2 f01 = __half22float2(__hadd2(u2h2(r0.x), u2h2(r1.x)));
            const float2 f23 = __half22float2(__hadd2(u2h2(r0.y), u2h2(r1.y)));
            a0 += f01.x; a1 += f01.y; a2 += f23.x; a3 += f23.y;
        }
        for (; e < s1; e += 4) {   // safety; unreachable with pad-8
            const int i0 = esrc[e + sub];
            const uint2 r = *(const uint2*)&xh[(size_t)i0 * H + fi];
            const float2 f01 = __half22float2(u2h2(r.x));
            const float2 f23 = __half22float2(u2h2(r.y));
            a0 += f01.x; a1 += f01.y; a2 += f23.x; a3 += f23.y;
        }
        #pragma unroll
        for (int o = 16; o < 64; o <<= 1) {
            a0 += __shfl_xor(a0, o);
            a1 += __shfl_xor(a1, o);
            a2 += __shfl_xor(a2, o);
            a3 += __shfl_xor(a3, o);
        }
        if (sub == 0) {
            const float4 self = *(const float4*)&x0[(size_t)n * H + fi];
            ushort4 o;
            o.x = f2h(ep * self.x + a0);
            o.y = f2h(ep * self.y + a1);
            o.z = f2h(ep * self.z + a2);
            o.w = f2h(ep * self.w + a3);
            *(ushort4*)&hpreh[(size_t)n * H + fi] = o;
        }
    }
}

// --- MFMA GEMM1 + BN stats: h1h[N,128] = fp16(hpreh @ W1 + b1) ---
// A single fp16, W split fp16 (hi+lo): 2 MFMAs per (A,W). Each wave: half cols.
extern "C" __global__ void __launch_bounds__(256) k_gemm1(
    const bfraw* __restrict__ hpreh,
    const bfraw* __restrict__ W1hi, const bfraw* __restrict__ W1lo,
    const float* __restrict__ b1, bfraw* __restrict__ h1h,
    double* __restrict__ gsum, double* __restrict__ gsq, int N)
{
    __shared__ float ss[TWOH], sq[TWOH];
    if (threadIdx.x < TWOH) { ss[threadIdx.x] = 0.f; sq[threadIdx.x] = 0.f; }
    __syncthreads();
    const int lane = threadIdx.x & 63;
    const int row = lane & 15;   // A row / B col / D col
    const int kg  = lane >> 4;   // k-group
    const int wpb = blockDim.x >> 6;
    const int wid = blockIdx.x * wpb + (threadIdx.x >> 6);
    const int wstride = gridDim.x * wpb;
    const int half = wid & 1;          // which 64 of the 128 cols
    const int cb = half * 4;           // col-tile base
    // preload B fragments: 2 k-chunks x 4 col-tiles, fp16 hi+lo
    v8h bhi[2][4], blo[2][4];
    #pragma unroll
    for (int kc = 0; kc < 2; ++kc)
        #pragma unroll
        for (int ct = 0; ct < 4; ++ct) {
            v8h bh, bl;
            #pragma unroll
            for (int i = 0; i < 8; ++i) {
                const int idx = (kc * 32 + kg * 8 + i) * TWOH + (cb + ct) * 16 + row;
                bh[i] = (_Float16)__ushort_as_half(W1hi[idx]);
                bl[i] = (_Float16)__ushort_as_half(W1lo[idx]);
            }
            bhi[kc][ct] = bh; blo[kc][ct] = bl;
        }
    float bcol[4];
    #pragma unroll
    for (int ct = 0; ct < 4; ++ct) bcol[ct] = b1[(cb + ct) * 16 + row];

    const int tiles = (N + 15) >> 4;
    const int tstride = wstride >> 1;
    float sacc[4], qacc[4];
    #pragma unroll
    for (int ct = 0; ct < 4; ++ct) { sacc[ct] = 0.f; qacc[ct] = 0.f; }

    for (int t = wid >> 1; t < tiles; t += tstride) {
        const int tb = t << 4;
        int nA = tb + row; if (nA >= N) nA = N - 1;
        h8cast a0c, a1c;
        a0c.q = *(const uint4*)&hpreh[(size_t)nA * H + kg * 8];
        a1c.q = *(const uint4*)&hpreh[(size_t)nA * H + 32 + kg * 8];
        const v8h a0 = a0c.h;
        const v8h a1 = a1c.h;
        v4f c[4];
        #pragma unroll
        for (int ct = 0; ct < 4; ++ct) {
            v4f cc = (v4f){0.f, 0.f, 0.f, 0.f};
            cc = __builtin_amdgcn_mfma_f32_16x16x32_f16(a0, bhi[0][ct], cc, 0, 0, 0);
            cc = __builtin_amdgcn_mfma_f32_16x16x32_f16(a1, bhi[1][ct], cc, 0, 0, 0);
            cc = __builtin_amdgcn_mfma_f32_16x16x32_f16(a0, blo[0][ct], cc, 0, 0, 0);
            cc = __builtin_amdgcn_mfma_f32_16x16x32_f16(a1, blo[1][ct], cc, 0, 0, 0);
            c[ct] = cc;
        }
        #pragma unroll
        for (int ct = 0; ct < 4; ++ct) {
            #pragma unroll
            for (int r = 0; r < 4; ++r) {
                const int node = tb + kg * 4 + r;  // D row
                if (node < N) {
                    const float v = c[ct][r] + bcol[ct];
                    h1h[(size_t)node * TWOH + (cb + ct) * 16 + row] = f2h(v);
                    sacc[ct] += v;
                    qacc[ct] += v * v;
                }
            }
        }
    }
    #pragma unroll
    for (int ct = 0; ct < 4; ++ct) {
        float s = sacc[ct];
        s += __shfl_xor(s, 16); s += __shfl_xor(s, 32);
        float q = qacc[ct];
        q += __shfl_xor(q, 16); q += __shfl_xor(q, 32);
        if (kg == 0) {
            atomicAdd(&ss[(cb + ct) * 16 + row], s);
            atomicAdd(&sq[(cb + ct) * 16 + row], q);
        }
    }
    __syncthreads();
    if (threadIdx.x < TWOH) {
        atomicAdd(&gsum[threadIdx.x], (double)ss[threadIdx.x]);
        atomicAdd(&gsq[threadIdx.x], (double)sq[threadIdx.x]);
    }
}

// ---------------- BN finalize: scale/shift ----------------
extern "C" __global__ void k_bnfin(const double* __restrict__ gsum,
    const double* __restrict__ gsq, const float* __restrict__ gamma,
    const float* __restrict__ beta, float* __restrict__ scsh, int N)
{
    const int j = threadIdx.x;
    if (j < TWOH) {
        const double mu = gsum[j] / N;
        const double var = gsq[j] / N - mu * mu;
        const float sc = gamma[j] * rsqrtf(fmaxf((float)var, 0.f) + 1e-5f);
        scsh[j] = sc;
        scsh[TWOH + j] = beta[j] - (float)mu * sc;
    }
}

// --- MFMA GEMM2 + fused BN/ReLU + residual: x0 += relu(h1*sc+sh) @ W2 + b2 ---
extern "C" __global__ void __launch_bounds__(256) k_gemm2(
    const bfraw* __restrict__ h1h, const float* __restrict__ scsh,
    const bfraw* __restrict__ W2hi, const bfraw* __restrict__ W2lo,
    const float* __restrict__ b2, float* __restrict__ x0,
    bfraw* __restrict__ xh, int N)
{
    __shared__ float scl[TWOH], shl[TWOH];  // 1 KB
    for (int i = threadIdx.x; i < TWOH; i += blockDim.x) {
        scl[i] = scsh[i];
        shl[i] = scsh[TWOH + i];
    }
    __syncthreads();
    const int lane = threadIdx.x & 63;
    const int row = lane & 15;
    const int kg  = lane >> 4;
    const int wpb = blockDim.x >> 6;
    const int wid = blockIdx.x * wpb + (threadIdx.x >> 6);
    const int wstride = gridDim.x * wpb;
    const int half = wid & 1;       // which 32 of the 64 cols
    const int cb = half * 2;        // col-tile base
    // preload B fragments: 4 k-chunks x 2 col-tiles, fp16 hi+lo
    v8h bhi[4][2], blo[4][2];
    #pragma unroll
    for (int kc = 0; kc < 4; ++kc)
        #pragma unroll
        for (int ct = 0; ct < 2; ++ct) {
            v8h bh, bl;
            #pragma unroll
            for (int i = 0; i < 8; ++i) {
                const int idx = (kc * 32 + kg * 8 + i) * H + (cb + ct) * 16 + row;
                bh[i] = (_Float16)__ushort_as_half(W2hi[idx]);
                bl[i] = (_Float16)__ushort_as_half(W2lo[idx]);
            }
            bhi[kc][ct] = bh; blo[kc][ct] = bl;
        }
    float bcol[2];
    #pragma unroll
    for (int ct = 0; ct < 2; ++ct) bcol[ct] = b2[(cb + ct) * 16 + row];
    // per-lane BN constants for this lane's 32 features (8 per k-chunk)
    float lsc[4][8], lsh[4][8];
    #pragma unroll
    for (int kc = 0; kc < 4; ++kc) {
        const int fb = kc * 32 + kg * 8;
        #pragma unroll
        for (int i = 0; i < 8; ++i) { lsc[kc][i] = scl[fb + i]; lsh[kc][i] = shl[fb + i]; }
    }

    const int tiles = (N + 15) >> 4;
    const int tstride = wstride >> 1;

    for (int t = wid >> 1; t < tiles; t += tstride) {
        const int tb = t << 4;
        int nA = tb + row; if (nA >= N) nA = N - 1;
        v8h a[4];
        #pragma unroll
        for (int kc = 0; kc < 4; ++kc) {
            const int fb = kc * 32 + kg * 8;
            h8cast hc;
            hc.q = *(const uint4*)&h1h[(size_t)nA * TWOH + fb];
            v8h va;
            #pragma unroll
            for (int i = 0; i < 8; ++i) {
                const float hv = (float)hc.h[i];
                va[i] = (_Float16)fmaxf(hv * lsc[kc][i] + lsh[kc][i], 0.f);
            }
            a[kc] = va;
        }
        v4f c[2];
        #pragma unroll
        for (int ct = 0; ct < 2; ++ct) {
            v4f cc = (v4f){0.f, 0.f, 0.f, 0.f};
            #pragma unroll
            for (int kc = 0; kc < 4; ++kc) {
                cc = __builtin_amdgcn_mfma_f32_16x16x32_f16(a[kc], bhi[kc][ct], cc, 0, 0, 0);
                cc = __builtin_amdgcn_mfma_f32_16x16x32_f16(a[kc], blo[kc][ct], cc, 0, 0, 0);
            }
            c[ct] = cc;
        }
        #pragma unroll
        for (int ct = 0; ct < 2; ++ct) {
            #pragma unroll
            for (int r = 0; r < 4; ++r) {
                const int node = tb + kg * 4 + r;
                if (node < N) {
                    const size_t idx = (size_t)node * H + (cb + ct) * 16 + row;
                    const float v = x0[idx] + c[ct][r] + bcol[ct];
                    x0[idx] = v;
                    xh[idx] = f2h(fmaxf(v, 0.f));   // relu pre-folded, fp16
                }
            }
        }
    }
}

// ---------------- pooling + output ----------------
extern "C" __global__ void k_initout(const float* __restrict__ bout,
    float* __restrict__ out)
{
    if (threadIdx.x < NGRAPH) out[threadIdx.x] = bout[0];
}

// segment-sum pooling: batch is SORTED. Each wave owns a contiguous node slab;
// lane l accumulates feature l; flush (reduce+atomic) only at graph boundaries.
extern "C" __global__ void __launch_bounds__(256) k_pool(
    const float* __restrict__ x0, const int* __restrict__ batch,
    const float* __restrict__ Wout, float* __restrict__ out, int N)
{
    const int lane = threadIdx.x & 63;
    const int wpb = blockDim.x >> 6;
    const int gw = blockIdx.x * wpb + (threadIdx.x >> 6);
    const int nw = gridDim.x * wpb;
    const int per = (N + nw - 1) / nw;
    const int n0 = gw * per;
    int n1 = n0 + per; if (n1 > N) n1 = N;
    if (n0 >= N) return;
    const float wv = Wout[lane];
    int cur = batch[n0];
    float acc = 0.f;
    for (int n = n0; n < n1; ++n) {
        const int g = batch[n];
        if (g != cur) {
            float v = acc * wv;
            #pragma unroll
            for (int o = 32; o > 0; o >>= 1) v += __shfl_down(v, o);
            if (lane == 0) atomicAdd(&out[cur], v);
            cur = g;
            acc = 0.f;
        }
        acc += x0[(size_t)n * H + lane];
    }
    float v = acc * wv;
    #pragma unroll
    for (int o = 32; o > 0; o >>= 1) v += __shfl_down(v, o);
    if (lane == 0) atomicAdd(&out[cur], v);
}

// ---------------- host driver ----------------
extern "C" void kernel_launch(void* const* d_in, const int* in_sizes, int n_in,
                              void* d_out, int out_size, void* d_ws, size_t ws_size,
                              hipStream_t stream)
{
    const float* x     = (const float*)d_in[0];
    const int*   ei    = (const int*)d_in[1];   // int32 per harness conversion
    const int*   batch = (const int*)d_in[2];   // int32 per harness conversion
    const float* Win   = (const float*)d_in[3];
    const float* bin   = (const float*)d_in[4];
    const float* W1s   = (const float*)d_in[5];
    const float* b1s   = (const float*)d_in[6];
    const float* gam   = (const float*)d_in[7];
    const float* bet   = (const float*)d_in[8];
    const float* W2s   = (const float*)d_in[9];
    const float* b2s   = (const float*)d_in[10];
    const float* epss  = (const float*)d_in[11];
    const float* Wout  = (const float*)d_in[12];
    const float* bout  = (const float*)d_in[13];

    const int N = in_sizes[0] / CIN;
    const int E = in_sizes[1] / 2;
    const int L = in_sizes[11];
    const int* src = ei;
    const int* dst = ei + E;
    const int NB = (N + BNODE - 1) >> BSH;   // final buckets (<= MAXNB)

    // workspace layout
    char* ws = (char*)d_ws;
    size_t off = 0;
    auto take = [&](size_t bytes) {
        void* p = ws + off;
        off += (bytes + 255) & ~(size_t)255;
        return p;
    };
    float*    x0     = (float*)take((size_t)N * H * 4);
    bfraw*    xh     = (bfraw*)take((size_t)(N + 1) * H * 2);  // fp16, +1 zero row
    bfraw*    hpreh  = (bfraw*)take((size_t)N * H * 2);        // fp16
    bfraw*    h1h    = (bfraw*)take((size_t)N * TWOH * 2);     // fp16
    unsigned* deg    = (unsigned*)take((size_t)N * 4);
    unsigned* indptr = (unsigned*)take((size_t)(N + 1) * 4);
    unsigned* cursor = (unsigned*)take((size_t)N * 4);
    int*      esrc   = (int*)take((size_t)(E + 8 * (N + 1)) * 4);  // padded to 8
    unsigned* bsum   = (unsigned*)take(4096);
    double*   gsum   = (double*)take(TWOH * 8 * 2); // gsum + gsq contiguous
    double*   gsq    = gsum + TWOH;
    float*    scsh   = (float*)take(2 * TWOH * 4);
    bfraw*    W1hi   = (bfraw*)take((size_t)L * H * TWOH * 2);
    bfraw*    W1lo   = (bfraw*)take((size_t)L * H * TWOH * 2);
    bfraw*    W2hi   = (bfraw*)take((size_t)L * TWOH * H * 2);
    bfraw*    W2lo   = (bfraw*)take((size_t)L * TWOH * H * 2);
    unsigned* bcnt   = (unsigned*)take((size_t)NBLK_PART * NB * 4);
    unsigned* btmp   = (unsigned*)take((size_t)NBLK_PART * NB * BCAP * 4);
    int*      oflow  = (int*)take((size_t)OCAP * 2 * 4);
    unsigned* ocnt   = (unsigned*)take(256);
    (void)ws_size; (void)n_in; (void)out_size;

    hipMemsetAsync(deg, 0, (size_t)N * 4, stream);
    hipMemsetAsync(ocnt, 0, 4, stream);
    hipMemsetAsync(xh + (size_t)N * H, 0, H * 2, stream);  // sentinel zero row
    k_input_gemm<<<512, 256, 0, stream>>>(x, Win, bin, x0, xh, N);
    k_cvtw<<<256, 256, 0, stream>>>(W1s, W2s, W1hi, W1lo, W2hi, W2lo, L * H * TWOH);
    k_bucket<<<NBLK_PART, 256, 0, stream>>>(src, dst, bcnt, btmp, deg, oflow, ocnt, E, NB);
    k_bhist<<<NB, 256, 0, stream>>>(bcnt, btmp, deg, N, NB);
    const int nb = (N + 1023) / 1024;
    k_scan1<<<nb, 256, 0, stream>>>(deg, indptr, bsum, N);
    k_scan2<<<1, 64, 0, stream>>>(bsum, nb, indptr, N);
    k_scan3<<<nb, 256, 0, stream>>>(indptr, bsum, cursor, N);
    k_bscat<<<NB, 256, 0, stream>>>(bcnt, btmp, indptr, cursor, esrc, N, NB);
    k_over<<<32, 256, 0, stream>>>(oflow, ocnt, cursor, esrc);
    k_pad<<<512, 256, 0, stream>>>(cursor, indptr, esrc, N);

    for (int l = 0; l < L; ++l) {
        hipMemsetAsync(gsum, 0, TWOH * 8 * 2, stream);
        k_agg<<<4096, 256, 0, stream>>>(x0, xh, esrc, indptr, epss + l, hpreh, N);
        k_gemm1<<<512, 256, 0, stream>>>(hpreh,
            W1hi + (size_t)l * H * TWOH, W1lo + (size_t)l * H * TWOH,
            b1s + (size_t)l * TWOH, h1h, gsum, gsq, N);
        k_bnfin<<<1, 128, 0, stream>>>(gsum, gsq, gam + (size_t)l * TWOH,
            bet + (size_t)l * TWOH, scsh, N);
        k_gemm2<<<512, 256, 0, stream>>>(h1h, scsh,
            W2hi + (size_t)l * TWOH * H, W2lo + (size_t)l * TWOH * H,
            b2s + (size_t)l * H, x0, xh, N);
    }

    k_initout<<<1, 64, 0, stream>>>(bout, (float*)d_out);
    k_pool<<<512, 256, 0, stream>>>(x0, batch, Wout, (float*)d_out, N);
}

// Round 15
// 456.455 us; speedup vs baseline: 1.3128x; 1.0279x over previous
//
#include <hip/hip_runtime.h>
#include <hip/hip_fp16.h>

#define H 64
#define CIN 32
#define TWOH 128
#define NGRAPH 64

// bucketed CSR build
#define BSH 7
#define BNODE 128
#define NBLK_PART 256
#define BCAP 32
#define MAXNB 2048
#define OCAP 65536

typedef unsigned short bfraw;
typedef _Float16 v8h __attribute__((ext_vector_type(8)));
typedef unsigned short v8u __attribute__((ext_vector_type(8)));
typedef float v4f __attribute__((ext_vector_type(4)));

union h8cast { v8u u; v8h h; uint4 q; };

// fp16 raw bits (RNE)
__device__ __forceinline__ bfraw f2h(float f) {
    return __half_as_ushort(__float2half(f));
}
__device__ __forceinline__ float h2f(bfraw u) {
    return __half2float(__ushort_as_half(u));
}
__device__ __forceinline__ __half2 u2h2(unsigned u) {
    union { unsigned u; __half2 h; } c; c.u = u; return c.h;
}
// split fp32 -> hi + lo fp16 (combined rel err ~2^-22)
__device__ __forceinline__ void f2h2(float f, _Float16& hi, _Float16& lo) {
    hi = (_Float16)f;
    lo = (_Float16)(f - (float)hi);
}

// ----- MFMA input GEMM: x0[N,64] = x[N,32] @ Win + bin; xh = fp16(relu(x0)) -----
extern "C" __global__ void __launch_bounds__(256) k_input_gemm(
    const float* __restrict__ x, const float* __restrict__ Win,
    const float* __restrict__ bin, float* __restrict__ x0,
    bfraw* __restrict__ xh, int N)
{
    const int lane = threadIdx.x & 63;
    const int row = lane & 15;
    const int kg  = lane >> 4;
    // B fragments: Win[32][64] split fp16 hi/lo, 1 k-chunk (K=32), 4 col-tiles
    v8h bhi[4], blo[4];
    #pragma unroll
    for (int ct = 0; ct < 4; ++ct) {
        v8h bh, bl;
        #pragma unroll
        for (int i = 0; i < 8; ++i) {
            const float w = Win[(kg * 8 + i) * H + ct * 16 + row];
            _Float16 h, l; f2h2(w, h, l);
            bh[i] = h; bl[i] = l;
        }
        bhi[ct] = bh; blo[ct] = bl;
    }
    float bcol[4];
    #pragma unroll
    for (int ct = 0; ct < 4; ++ct) bcol[ct] = bin[ct * 16 + row];

    const int wpb = blockDim.x >> 6;
    const int wid = blockIdx.x * wpb + (threadIdx.x >> 6);
    const int wstride = gridDim.x * wpb;
    const int tiles = (N + 15) >> 4;
    for (int t = wid; t < tiles; t += wstride) {
        const int tb = t << 4;
        int nA = tb + row; if (nA >= N) nA = N - 1;
        v8h a;
        #pragma unroll
        for (int i = 0; i < 8; ++i)
            a[i] = (_Float16)x[(size_t)nA * CIN + kg * 8 + i];
        v4f c[4];
        #pragma unroll
        for (int ct = 0; ct < 4; ++ct) {
            v4f cc = (v4f){0.f, 0.f, 0.f, 0.f};
            cc = __builtin_amdgcn_mfma_f32_16x16x32_f16(a, bhi[ct], cc, 0, 0, 0);
            cc = __builtin_amdgcn_mfma_f32_16x16x32_f16(a, blo[ct], cc, 0, 0, 0);
            c[ct] = cc;
        }
        #pragma unroll
        for (int ct = 0; ct < 4; ++ct) {
            #pragma unroll
            for (int r = 0; r < 4; ++r) {
                const int node = tb + kg * 4 + r;
                if (node < N) {
                    const float v = c[ct][r] + bcol[ct];
                    const size_t idx = (size_t)node * H + ct * 16 + row;
                    x0[idx] = v;
                    xh[idx] = f2h(fmaxf(v, 0.f));   // relu pre-folded, fp16
                }
            }
        }
    }
}

// ------------- weight conversion to split fp16 (all layers, once) -------------
extern "C" __global__ void k_cvtw(const float* __restrict__ W1s,
    const float* __restrict__ W2s, bfraw* __restrict__ W1hi,
    bfraw* __restrict__ W1lo, bfraw* __restrict__ W2hi,
    bfraw* __restrict__ W2lo, int total)  // total = L*H*TWOH
{
    int i = blockIdx.x * blockDim.x + threadIdx.x;
    const int st = gridDim.x * blockDim.x;
    for (; i < total; i += st) {
        {
            const float w = W1s[i];
            const bfraw hb = f2h(w);
            W1hi[i] = hb;
            W1lo[i] = f2h(w - h2f(hb));
        }
        {
            const float w = W2s[i];
            const bfraw hb = f2h(w);
            W2hi[i] = hb;
            W2lo[i] = f2h(w - h2f(hb));
        }
    }
}

// ---------------- block-private bucket partition (pass A) ----------------
__device__ __forceinline__ void bput(int s, int d, unsigned* __restrict__ lcnt,
    unsigned* __restrict__ myTmp, unsigned* __restrict__ deg,
    int* __restrict__ oflow, unsigned* __restrict__ ocnt)
{
    const int b = d >> BSH;
    const unsigned pos = atomicAdd(&lcnt[b], 1u);   // LDS atomic
    if (pos < BCAP) {
        myTmp[b * BCAP + pos] = (unsigned)s | ((unsigned)(d & (BNODE - 1)) << 20);
    } else {
        const unsigned o = atomicAdd(ocnt, 1u);
        if (o < OCAP) {
            oflow[2 * o] = s; oflow[2 * o + 1] = d;
            atomicAdd(&deg[d], 1u);
        }
    }
}

extern "C" __global__ void __launch_bounds__(256) k_bucket(
    const int* __restrict__ src, const int* __restrict__ dst,
    unsigned* __restrict__ bcnt, unsigned* __restrict__ btmp,
    unsigned* __restrict__ deg, int* __restrict__ oflow,
    unsigned* __restrict__ ocnt, int E, int NBck)
{
    __shared__ unsigned lcnt[MAXNB];  // 8 KB (NBck <= 2048)
    for (int i = threadIdx.x; i < NBck; i += blockDim.x) lcnt[i] = 0u;
    __syncthreads();
    unsigned* __restrict__ myTmp = btmp + (size_t)blockIdx.x * NBck * BCAP;
    const int tid0 = blockIdx.x * blockDim.x + threadIdx.x;
    const int st = gridDim.x * blockDim.x;
    const int E4 = E >> 2;
    const int4* s4 = (const int4*)src;
    const int4* d4 = (const int4*)dst;
    for (int j = tid0; j < E4; j += st) {
        const int4 sv = s4[j];
        const int4 dv = d4[j];
        bput(sv.x, dv.x, lcnt, myTmp, deg, oflow, ocnt);
        bput(sv.y, dv.y, lcnt, myTmp, deg, oflow, ocnt);
        bput(sv.z, dv.z, lcnt, myTmp, deg, oflow, ocnt);
        bput(sv.w, dv.w, lcnt, myTmp, deg, oflow, ocnt);
    }
    for (int j = (E4 << 2) + tid0; j < E; j += st)
        bput(src[j], dst[j], lcnt, myTmp, deg, oflow, ocnt);
    __syncthreads();
    unsigned* __restrict__ myCnt = bcnt + (size_t)blockIdx.x * NBck;
    for (int i = threadIdx.x; i < NBck; i += blockDim.x) {
        const unsigned c = lcnt[i];
        myCnt[i] = (c < BCAP) ? c : BCAP;
    }
}

// ---------------- per-bucket degree histogram ----------------
extern "C" __global__ void __launch_bounds__(256) k_bhist(
    const unsigned* __restrict__ bcnt, const unsigned* __restrict__ btmp,
    unsigned* __restrict__ deg, int N, int NBck)
{
    __shared__ unsigned hist[BNODE];
    const int b = blockIdx.x;
    for (int i = threadIdx.x; i < BNODE; i += blockDim.x) hist[i] = 0u;
    __syncthreads();
    for (int blk = threadIdx.x; blk < NBLK_PART; blk += blockDim.x) {
        const unsigned cnt = bcnt[(size_t)blk * NBck + b];
        const unsigned* p = btmp + ((size_t)blk * NBck + b) * BCAP;
        for (unsigned j = 0; j < cnt; ++j)
            atomicAdd(&hist[p[j] >> 20], 1u);
    }
    __syncthreads();
    const int base = b << BSH;
    for (int i = threadIdx.x; i < BNODE; i += blockDim.x)
        if (base + i < N) {
            const unsigned h = hist[i];
            if (h) atomicAdd(&deg[base + i], h);
        }
}

extern "C" __global__ void k_scan1(const unsigned* __restrict__ deg,
    unsigned* __restrict__ indptr, unsigned* __restrict__ bsum, int N)
{
    __shared__ unsigned s[256];
    const int tid = threadIdx.x;
    const int base = blockIdx.x * 1024 + tid * 4;
    unsigned d[4];
    #pragma unroll
    for (int j = 0; j < 4; ++j)
        d[j] = (base + j < N) ? ((deg[base + j] + 7u) & ~7u) : 0u;  // pad to 8
    unsigned t = d[0] + d[1] + d[2] + d[3];
    s[tid] = t;
    __syncthreads();
    for (int o = 1; o < 256; o <<= 1) {
        unsigned v = (tid >= o) ? s[tid - o] : 0u;
        __syncthreads();
        s[tid] += v;
        __syncthreads();
    }
    unsigned run = (tid == 0) ? 0u : s[tid - 1];
    if (tid == 255) bsum[blockIdx.x] = s[255];
    #pragma unroll
    for (int j = 0; j < 4; ++j) {
        if (base + j < N) indptr[base + j] = run;
        run += d[j];
    }
}

// scan2 + out-init fused (out[g] = bout[0]; later pool adds are commutative)
extern "C" __global__ void k_scan2(unsigned* bsum, int nb,
    unsigned* __restrict__ indptr, int N,
    const float* __restrict__ bout, float* __restrict__ out)
{
    if (threadIdx.x < NGRAPH) out[threadIdx.x] = bout[0];
    if (threadIdx.x == 0) {
        unsigned run = 0;
        for (int i = 0; i < nb; ++i) { unsigned v = bsum[i]; bsum[i] = run; run += v; }
        indptr[N] = run;  // total padded edges
    }
}

extern "C" __global__ void k_scan3(unsigned* __restrict__ indptr,
    const unsigned* __restrict__ bsum, unsigned* __restrict__ cursor, int N)
{
    const int base = blockIdx.x * 1024 + threadIdx.x * 4;
    const unsigned boff = bsum[blockIdx.x];
    #pragma unroll
    for (int j = 0; j < 4; ++j) {
        const int idx = base + j;
        if (idx < N) {
            const unsigned v = indptr[idx] + boff;
            indptr[idx] = v;
            cursor[idx] = v;
        }
    }
}

// ---------------- per-bucket scatter to final CSR (pass B) ----------------
extern "C" __global__ void __launch_bounds__(256) k_bscat(
    const unsigned* __restrict__ bcnt, const unsigned* __restrict__ btmp,
    const unsigned* __restrict__ indptr, unsigned* __restrict__ cursor,
    int* __restrict__ esrc, int N, int NBck)
{
    __shared__ unsigned lcur[BNODE];
    const int b = blockIdx.x;
    const int base = b << BSH;
    for (int i = threadIdx.x; i < BNODE; i += blockDim.x)
        lcur[i] = (base + i < N) ? indptr[base + i] : 0u;
    __syncthreads();
    for (int blk = threadIdx.x; blk < NBLK_PART; blk += blockDim.x) {
        const unsigned cnt = bcnt[(size_t)blk * NBck + b];
        const unsigned* p = btmp + ((size_t)blk * NBck + b) * BCAP;
        for (unsigned j = 0; j < cnt; ++j) {
            const unsigned e = p[j];
            const unsigned pos = atomicAdd(&lcur[e >> 20], 1u);
            esrc[pos] = (int)(e & 0xFFFFFu);
        }
    }
    __syncthreads();
    for (int i = threadIdx.x; i < BNODE; i += blockDim.x)
        if (base + i < N) cursor[base + i] = lcur[i];
}

// overflow edges (expected none) via global cursor
extern "C" __global__ void k_over(const int* __restrict__ oflow,
    const unsigned* __restrict__ ocnt, unsigned* __restrict__ cursor,
    int* __restrict__ esrc)
{
    unsigned n = *ocnt; if (n > OCAP) n = OCAP;
    int i = blockIdx.x * blockDim.x + threadIdx.x;
    const int st = gridDim.x * blockDim.x;
    for (; (unsigned)i < n; i += st) {
        const int s = oflow[2 * i], d = oflow[2 * i + 1];
        const unsigned pos = atomicAdd(&cursor[d], 1u);
        esrc[pos] = s;
    }
}

// fill padded slots with sentinel N (zero row)
extern "C" __global__ void k_pad(const unsigned* __restrict__ cursor,
    const unsigned* __restrict__ indptr, int* __restrict__ esrc, int N)
{
    int n = blockIdx.x * blockDim.x + threadIdx.x;
    const int st = gridDim.x * blockDim.x;
    for (; n < N; n += st) {
        const unsigned end = indptr[n + 1];
        for (unsigned p = cursor[n]; p < end; ++p) esrc[p] = N;
    }
}

// --- gather: hpreh = fp16((1+eps)*x0 + sum xh[src]); degrees padded to 8 ---
extern "C" __global__ void __launch_bounds__(256) k_agg(
    const float* __restrict__ x0, const bfraw* __restrict__ xh,
    const int* __restrict__ esrc, const unsigned* __restrict__ indptr,
    const float* __restrict__ epsp, bfraw* __restrict__ hpreh, int N)
{
    const int lane = threadIdx.x & 63;
    const int sub = lane >> 4;          // 0..3 : which edge of the group
    const int fi = (lane & 15) << 2;    // feature base (4 features)
    const int wpb = blockDim.x >> 6;
    int w = blockIdx.x * wpb + (threadIdx.x >> 6);
    const int wstride = gridDim.x * wpb;
    const float ep = 1.f + epsp[0];
    for (int n = w; n < N; n += wstride) {
        const unsigned s0 = indptr[n];
        const unsigned s1 = indptr[n + 1];   // padded: (s1-s0)%8==0
        float a0 = 0.f, a1 = 0.f, a2 = 0.f, a3 = 0.f;
        unsigned e = s0;
        for (; e + 16 <= s1; e += 16) {
            int idx[4];
            #pragma unroll
            for (int j = 0; j < 4; ++j) idx[j] = esrc[e + 4 * j + sub];
            uint2 r[4];
            #pragma unroll
            for (int j = 0; j < 4; ++j)
                r[j] = *(const uint2*)&xh[(size_t)idx[j] * H + fi];
            const __half2 s01 = __hadd2(__hadd2(u2h2(r[0].x), u2h2(r[1].x)),
                                        __hadd2(u2h2(r[2].x), u2h2(r[3].x)));
            const __half2 s23 = __hadd2(__hadd2(u2h2(r[0].y), u2h2(r[1].y)),
                                        __hadd2(u2h2(r[2].y), u2h2(r[3].y)));
            const float2 f01 = __half22float2(s01);
            const float2 f23 = __half22float2(s23);
            a0 += f01.x; a1 += f01.y; a2 += f23.x; a3 += f23.y;
        }
        for (; e + 8 <= s1; e += 8) {
            const int i0 = esrc[e + sub];
            const int i1 = esrc[e + 4 + sub];
            const uint2 r0 = *(const uint2*)&xh[(size_t)i0 * H + fi];
            const uint2 r1 = *(const uint2*)&xh[(size_t)i1 * H + fi];
            const float2 f01 = __half22float2(__hadd2(u2h2(r0.x), u2h2(r1.x)));
            const float2 f23 = __half22float2(__hadd2(u2h2(r0.y), u2h2(r1.y)));
            a0 += f01.x; a1 += f01.y; a2 += f23.x; a3 += f23.y;
        }
        for (; e < s1; e += 4) {   // safety; unreachable with pad-8
            const int i0 = esrc[e + sub];
            const uint2 r = *(const uint2*)&xh[(size_t)i0 * H + fi];
            const float2 f01 = __half22float2(u2h2(r.x));
            const float2 f23 = __half22float2(u2h2(r.y));
            a0 += f01.x; a1 += f01.y; a2 += f23.x; a3 += f23.y;
        }
        #pragma unroll
        for (int o = 16; o < 64; o <<= 1) {
            a0 += __shfl_xor(a0, o);
            a1 += __shfl_xor(a1, o);
            a2 += __shfl_xor(a2, o);
            a3 += __shfl_xor(a3, o);
        }
        if (sub == 0) {
            const float4 self = *(const float4*)&x0[(size_t)n * H + fi];
            ushort4 o;
            o.x = f2h(ep * self.x + a0);
            o.y = f2h(ep * self.y + a1);
            o.z = f2h(ep * self.z + a2);
            o.w = f2h(ep * self.w + a3);
            *(ushort4*)&hpreh[(size_t)n * H + fi] = o;
        }
    }
}

// --- MFMA GEMM1 + BN stats: h1h[N,128] = fp16(hpreh @ W1 + b1) ---
// A single fp16, W split fp16 (hi+lo): 2 MFMAs per (A,W). Each wave: half cols.
extern "C" __global__ void __launch_bounds__(256) k_gemm1(
    const bfraw* __restrict__ hpreh,
    const bfraw* __restrict__ W1hi, const bfraw* __restrict__ W1lo,
    const float* __restrict__ b1, bfraw* __restrict__ h1h,
    double* __restrict__ gsum, double* __restrict__ gsq, int N)
{
    __shared__ float ss[TWOH], sq[TWOH];
    if (threadIdx.x < TWOH) { ss[threadIdx.x] = 0.f; sq[threadIdx.x] = 0.f; }
    __syncthreads();
    const int lane = threadIdx.x & 63;
    const int row = lane & 15;   // A row / B col / D col
    const int kg  = lane >> 4;   // k-group
    const int wpb = blockDim.x >> 6;
    const int wid = blockIdx.x * wpb + (threadIdx.x >> 6);
    const int wstride = gridDim.x * wpb;
    const int half = wid & 1;          // which 64 of the 128 cols
    const int cb = half * 4;           // col-tile base
    // preload B fragments: 2 k-chunks x 4 col-tiles, fp16 hi+lo
    v8h bhi[2][4], blo[2][4];
    #pragma unroll
    for (int kc = 0; kc < 2; ++kc)
        #pragma unroll
        for (int ct = 0; ct < 4; ++ct) {
            v8h bh, bl;
            #pragma unroll
            for (int i = 0; i < 8; ++i) {
                const int idx = (kc * 32 + kg * 8 + i) * TWOH + (cb + ct) * 16 + row;
                bh[i] = (_Float16)__ushort_as_half(W1hi[idx]);
                bl[i] = (_Float16)__ushort_as_half(W1lo[idx]);
            }
            bhi[kc][ct] = bh; blo[kc][ct] = bl;
        }
    float bcol[4];
    #pragma unroll
    for (int ct = 0; ct < 4; ++ct) bcol[ct] = b1[(cb + ct) * 16 + row];

    const int tiles = (N + 15) >> 4;
    const int tstride = wstride >> 1;
    float sacc[4], qacc[4];
    #pragma unroll
    for (int ct = 0; ct < 4; ++ct) { sacc[ct] = 0.f; qacc[ct] = 0.f; }

    for (int t = wid >> 1; t < tiles; t += tstride) {
        const int tb = t << 4;
        int nA = tb + row; if (nA >= N) nA = N - 1;
        h8cast a0c, a1c;
        a0c.q = *(const uint4*)&hpreh[(size_t)nA * H + kg * 8];
        a1c.q = *(const uint4*)&hpreh[(size_t)nA * H + 32 + kg * 8];
        const v8h a0 = a0c.h;
        const v8h a1 = a1c.h;
        v4f c[4];
        #pragma unroll
        for (int ct = 0; ct < 4; ++ct) {
            v4f cc = (v4f){0.f, 0.f, 0.f, 0.f};
            cc = __builtin_amdgcn_mfma_f32_16x16x32_f16(a0, bhi[0][ct], cc, 0, 0, 0);
            cc = __builtin_amdgcn_mfma_f32_16x16x32_f16(a1, bhi[1][ct], cc, 0, 0, 0);
            cc = __builtin_amdgcn_mfma_f32_16x16x32_f16(a0, blo[0][ct], cc, 0, 0, 0);
            cc = __builtin_amdgcn_mfma_f32_16x16x32_f16(a1, blo[1][ct], cc, 0, 0, 0);
            c[ct] = cc;
        }
        #pragma unroll
        for (int ct = 0; ct < 4; ++ct) {
            #pragma unroll
            for (int r = 0; r < 4; ++r) {
                const int node = tb + kg * 4 + r;  // D row
                if (node < N) {
                    const float v = c[ct][r] + bcol[ct];
                    h1h[(size_t)node * TWOH + (cb + ct) * 16 + row] = f2h(v);
                    sacc[ct] += v;
                    qacc[ct] += v * v;
                }
            }
        }
    }
    #pragma unroll
    for (int ct = 0; ct < 4; ++ct) {
        float s = sacc[ct];
        s += __shfl_xor(s, 16); s += __shfl_xor(s, 32);
        float q = qacc[ct];
        q += __shfl_xor(q, 16); q += __shfl_xor(q, 32);
        if (kg == 0) {
            atomicAdd(&ss[(cb + ct) * 16 + row], s);
            atomicAdd(&sq[(cb + ct) * 16 + row], q);
        }
    }
    __syncthreads();
    if (threadIdx.x < TWOH) {
        atomicAdd(&gsum[threadIdx.x], (double)ss[threadIdx.x]);
        atomicAdd(&gsq[threadIdx.x], (double)sq[threadIdx.x]);
    }
}

// --- MFMA GEMM2 + BN finalize (in prologue) + BN/ReLU + residual ---
extern "C" __global__ void __launch_bounds__(256) k_gemm2(
    const bfraw* __restrict__ h1h,
    const double* __restrict__ gsum, const double* __restrict__ gsq,
    const float* __restrict__ gamma, const float* __restrict__ beta,
    const bfraw* __restrict__ W2hi, const bfraw* __restrict__ W2lo,
    const float* __restrict__ b2, float* __restrict__ x0,
    bfraw* __restrict__ xh, int N)
{
    __shared__ float scl[TWOH], shl[TWOH];  // 1 KB
    if (threadIdx.x < TWOH) {
        const int j = threadIdx.x;
        const double mu = gsum[j] / N;
        const double var = gsq[j] / N - mu * mu;
        const float sc = gamma[j] * rsqrtf(fmaxf((float)var, 0.f) + 1e-5f);
        scl[j] = sc;
        shl[j] = beta[j] - (float)mu * sc;
    }
    __syncthreads();
    const int lane = threadIdx.x & 63;
    const int row = lane & 15;
    const int kg  = lane >> 4;
    const int wpb = blockDim.x >> 6;
    const int wid = blockIdx.x * wpb + (threadIdx.x >> 6);
    const int wstride = gridDim.x * wpb;
    const int half = wid & 1;       // which 32 of the 64 cols
    const int cb = half * 2;        // col-tile base
    // preload B fragments: 4 k-chunks x 2 col-tiles, fp16 hi+lo
    v8h bhi[4][2], blo[4][2];
    #pragma unroll
    for (int kc = 0; kc < 4; ++kc)
        #pragma unroll
        for (int ct = 0; ct < 2; ++ct) {
            v8h bh, bl;
            #pragma unroll
            for (int i = 0; i < 8; ++i) {
                const int idx = (kc * 32 + kg * 8 + i) * H + (cb + ct) * 16 + row;
                bh[i] = (_Float16)__ushort_as_half(W2hi[idx]);
                bl[i] = (_Float16)__ushort_as_half(W2lo[idx]);
            }
            bhi[kc][ct] = bh; blo[kc][ct] = bl;
        }
    float bcol[2];
    #pragma unroll
    for (int ct = 0; ct < 2; ++ct) bcol[ct] = b2[(cb + ct) * 16 + row];
    // per-lane BN constants for this lane's 32 features (8 per k-chunk)
    float lsc[4][8], lsh[4][8];
    #pragma unroll
    for (int kc = 0; kc < 4; ++kc) {
        const int fb = kc * 32 + kg * 8;
        #pragma unroll
        for (int i = 0; i < 8; ++i) { lsc[kc][i] = scl[fb + i]; lsh[kc][i] = shl[fb + i]; }
    }

    const int tiles = (N + 15) >> 4;
    const int tstride = wstride >> 1;

    for (int t = wid >> 1; t < tiles; t += tstride) {
        const int tb = t << 4;
        int nA = tb + row; if (nA >= N) nA = N - 1;
        v8h a[4];
        #pragma unroll
        for (int kc = 0; kc < 4; ++kc) {
            const int fb = kc * 32 + kg * 8;
            h8cast hc;
            hc.q = *(const uint4*)&h1h[(size_t)nA * TWOH + fb];
            v8h va;
            #pragma unroll
            for (int i = 0; i < 8; ++i) {
                const float hv = (float)hc.h[i];
                va[i] = (_Float16)fmaxf(hv * lsc[kc][i] + lsh[kc][i], 0.f);
            }
            a[kc] = va;
        }
        v4f c[2];
        #pragma unroll
        for (int ct = 0; ct < 2; ++ct) {
            v4f cc = (v4f){0.f, 0.f, 0.f, 0.f};
            #pragma unroll
            for (int kc = 0; kc < 4; ++kc) {
                cc = __builtin_amdgcn_mfma_f32_16x16x32_f16(a[kc], bhi[kc][ct], cc, 0, 0, 0);
                cc = __builtin_amdgcn_mfma_f32_16x16x32_f16(a[kc], blo[kc][ct], cc, 0, 0, 0);
            }
            c[ct] = cc;
        }
        #pragma unroll
        for (int ct = 0; ct < 2; ++ct) {
            #pragma unroll
            for (int r = 0; r < 4; ++r) {
                const int node = tb + kg * 4 + r;
                if (node < N) {
                    const size_t idx = (size_t)node * H + (cb + ct) * 16 + row;
                    const float v = x0[idx] + c[ct][r] + bcol[ct];
                    x0[idx] = v;
                    xh[idx] = f2h(fmaxf(v, 0.f));   // relu pre-folded, fp16
                }
            }
        }
    }
}

// segment-sum pooling: batch is SORTED. Each wave owns a contiguous node slab;
// lane l accumulates feature l; flush (reduce+atomic) only at graph boundaries.
extern "C" __global__ void __launch_bounds__(256) k_pool(
    const float* __restrict__ x0, const int* __restrict__ batch,
    const float* __restrict__ Wout, float* __restrict__ out, int N)
{
    const int lane = threadIdx.x & 63;
    const int wpb = blockDim.x >> 6;
    const int gw = blockIdx.x * wpb + (threadIdx.x >> 6);
    const int nw = gridDim.x * wpb;
    const int per = (N + nw - 1) / nw;
    const int n0 = gw * per;
    int n1 = n0 + per; if (n1 > N) n1 = N;
    if (n0 >= N) return;
    const float wv = Wout[lane];
    int cur = batch[n0];
    float acc = 0.f;
    for (int n = n0; n < n1; ++n) {
        const int g = batch[n];
        if (g != cur) {
            float v = acc * wv;
            #pragma unroll
            for (int o = 32; o > 0; o >>= 1) v += __shfl_down(v, o);
            if (lane == 0) atomicAdd(&out[cur], v);
            cur = g;
            acc = 0.f;
        }
        acc += x0[(size_t)n * H + lane];
    }
    float v = acc * wv;
    #pragma unroll
    for (int o = 32; o > 0; o >>= 1) v += __shfl_down(v, o);
    if (lane == 0) atomicAdd(&out[cur], v);
}

// ---------------- host driver ----------------
extern "C" void kernel_launch(void* const* d_in, const int* in_sizes, int n_in,
                              void* d_out, int out_size, void* d_ws, size_t ws_size,
                              hipStream_t stream)
{
    const float* x     = (const float*)d_in[0];
    const int*   ei    = (const int*)d_in[1];   // int32 per harness conversion
    const int*   batch = (const int*)d_in[2];   // int32 per harness conversion
    const float* Win   = (const float*)d_in[3];
    const float* bin   = (const float*)d_in[4];
    const float* W1s   = (const float*)d_in[5];
    const float* b1s   = (const float*)d_in[6];
    const float* gam   = (const float*)d_in[7];
    const float* bet   = (const float*)d_in[8];
    const float* W2s   = (const float*)d_in[9];
    const float* b2s   = (const float*)d_in[10];
    const float* epss  = (const float*)d_in[11];
    const float* Wout  = (const float*)d_in[12];
    const float* bout  = (const float*)d_in[13];

    const int N = in_sizes[0] / CIN;
    const int E = in_sizes[1] / 2;
    const int L = in_sizes[11];
    const int* src = ei;
    const int* dst = ei + E;
    const int NB = (N + BNODE - 1) >> BSH;   // final buckets (<= MAXNB)

    // workspace layout
    char* ws = (char*)d_ws;
    size_t off = 0;
    auto take = [&](size_t bytes) {
        void* p = ws + off;
        off += (bytes + 255) & ~(size_t)255;
        return p;
    };
    float*    x0     = (float*)take((size_t)N * H * 4);
    bfraw*    xh     = (bfraw*)take((size_t)(N + 1) * H * 2);  // fp16, +1 zero row
    bfraw*    hpreh  = (bfraw*)take((size_t)N * H * 2);        // fp16
    bfraw*    h1h    = (bfraw*)take((size_t)N * TWOH * 2);     // fp16
    unsigned* deg    = (unsigned*)take((size_t)N * 4);
    unsigned* indptr = (unsigned*)take((size_t)(N + 1) * 4);
    unsigned* cursor = (unsigned*)take((size_t)N * 4);
    int*      esrc   = (int*)take((size_t)(E + 8 * (N + 1)) * 4);  // padded to 8
    unsigned* bsum   = (unsigned*)take(4096);
    double*   gsumAll = (double*)take((size_t)8 * TWOH * 8 * 2); // per-layer gsum+gsq
    float*    scsh   = (float*)take(2 * TWOH * 4);
    bfraw*    W1hi   = (bfraw*)take((size_t)L * H * TWOH * 2);
    bfraw*    W1lo   = (bfraw*)take((size_t)L * H * TWOH * 2);
    bfraw*    W2hi   = (bfraw*)take((size_t)L * TWOH * H * 2);
    bfraw*    W2lo   = (bfraw*)take((size_t)L * TWOH * H * 2);
    unsigned* bcnt   = (unsigned*)take((size_t)NBLK_PART * NB * 4);
    unsigned* btmp   = (unsigned*)take((size_t)NBLK_PART * NB * BCAP * 4);
    int*      oflow  = (int*)take((size_t)OCAP * 2 * 4);
    unsigned* ocnt   = (unsigned*)take(256);
    (void)ws_size; (void)n_in; (void)out_size; (void)scsh;

    hipMemsetAsync(deg, 0, (size_t)N * 4, stream);
    hipMemsetAsync(ocnt, 0, 4, stream);
    hipMemsetAsync(xh + (size_t)N * H, 0, H * 2, stream);  // sentinel zero row
    hipMemsetAsync(gsumAll, 0, (size_t)8 * TWOH * 8 * 2, stream);  // all layers
    k_input_gemm<<<512, 256, 0, stream>>>(x, Win, bin, x0, xh, N);
    k_cvtw<<<256, 256, 0, stream>>>(W1s, W2s, W1hi, W1lo, W2hi, W2lo, L * H * TWOH);
    k_bucket<<<NBLK_PART, 256, 0, stream>>>(src, dst, bcnt, btmp, deg, oflow, ocnt, E, NB);
    k_bhist<<<NB, 256, 0, stream>>>(bcnt, btmp, deg, N, NB);
    const int nb = (N + 1023) / 1024;
    k_scan1<<<nb, 256, 0, stream>>>(deg, indptr, bsum, N);
    k_scan2<<<1, 64, 0, stream>>>(bsum, nb, indptr, N, bout, (float*)d_out);
    k_scan3<<<nb, 256, 0, stream>>>(indptr, bsum, cursor, N);
    k_bscat<<<NB, 256, 0, stream>>>(bcnt, btmp, indptr, cursor, esrc, N, NB);
    k_over<<<32, 256, 0, stream>>>(oflow, ocnt, cursor, esrc);
    k_pad<<<512, 256, 0, stream>>>(cursor, indptr, esrc, N);

    for (int l = 0; l < L; ++l) {
        double* gsum = gsumAll + (size_t)l * 2 * TWOH;
        double* gsq  = gsum + TWOH;
        k_agg<<<4096, 256, 0, stream>>>(x0, xh, esrc, indptr, epss + l, hpreh, N);
        k_gemm1<<<512, 256, 0, stream>>>(hpreh,
            W1hi + (size_t)l * H * TWOH, W1lo + (size_t)l * H * TWOH,
            b1s + (size_t)l * TWOH, h1h, gsum, gsq, N);
        k_gemm2<<<512, 256, 0, stream>>>(h1h, gsum, gsq,
            gam + (size_t)l * TWOH, bet + (size_t)l * TWOH,
            W2hi + (size_t)l * TWOH * H, W2lo + (size_t)l * TWOH * H,
            b2s + (size_t)l * H, x0, xh, N);
    }

    k_pool<<<512, 256, 0, stream>>>(x0, batch, Wout, (float*)d_out, N);
}

// Round 16
// 447.207 us; speedup vs baseline: 1.3400x; 1.0207x over previous
//
#include <hip/hip_runtime.h>
#include <hip/hip_fp16.h>

#define H 64
#define CIN 32
#define TWOH 128
#define NGRAPH 64

// bucketed CSR build
#define BSH 7
#define BNODE 128
#define NBLK_PART 256
#define BCAP 32
#define MAXNB 2048
#define OCAP 65536

typedef unsigned short bfraw;
typedef _Float16 v8h __attribute__((ext_vector_type(8)));
typedef unsigned short v8u __attribute__((ext_vector_type(8)));
typedef float v4f __attribute__((ext_vector_type(4)));

union h8cast { v8u u; v8h h; uint4 q; };

// fp16 raw bits (RNE)
__device__ __forceinline__ bfraw f2h(float f) {
    return __half_as_ushort(__float2half(f));
}
__device__ __forceinline__ float h2f(bfraw u) {
    return __half2float(__ushort_as_half(u));
}
__device__ __forceinline__ __half2 u2h2(unsigned u) {
    union { unsigned u; __half2 h; } c; c.u = u; return c.h;
}
// split fp32 -> hi + lo fp16 (combined rel err ~2^-22)
__device__ __forceinline__ void f2h2(float f, _Float16& hi, _Float16& lo) {
    hi = (_Float16)f;
    lo = (_Float16)(f - (float)hi);
}

// ----- MFMA input GEMM: x0[N,64] = x[N,32] @ Win + bin; xh = fp16(relu(x0)) -----
extern "C" __global__ void __launch_bounds__(256) k_input_gemm(
    const float* __restrict__ x, const float* __restrict__ Win,
    const float* __restrict__ bin, float* __restrict__ x0,
    bfraw* __restrict__ xh, int N)
{
    const int lane = threadIdx.x & 63;
    const int row = lane & 15;
    const int kg  = lane >> 4;
    // B fragments: Win[32][64] split fp16 hi/lo, 1 k-chunk (K=32), 4 col-tiles
    v8h bhi[4], blo[4];
    #pragma unroll
    for (int ct = 0; ct < 4; ++ct) {
        v8h bh, bl;
        #pragma unroll
        for (int i = 0; i < 8; ++i) {
            const float w = Win[(kg * 8 + i) * H + ct * 16 + row];
            _Float16 h, l; f2h2(w, h, l);
            bh[i] = h; bl[i] = l;
        }
        bhi[ct] = bh; blo[ct] = bl;
    }
    float bcol[4];
    #pragma unroll
    for (int ct = 0; ct < 4; ++ct) bcol[ct] = bin[ct * 16 + row];

    const int wpb = blockDim.x >> 6;
    const int wid = blockIdx.x * wpb + (threadIdx.x >> 6);
    const int wstride = gridDim.x * wpb;
    const int tiles = (N + 15) >> 4;
    for (int t = wid; t < tiles; t += wstride) {
        const int tb = t << 4;
        int nA = tb + row; if (nA >= N) nA = N - 1;
        v8h a;
        #pragma unroll
        for (int i = 0; i < 8; ++i)
            a[i] = (_Float16)x[(size_t)nA * CIN + kg * 8 + i];
        v4f c[4];
        #pragma unroll
        for (int ct = 0; ct < 4; ++ct) {
            v4f cc = (v4f){0.f, 0.f, 0.f, 0.f};
            cc = __builtin_amdgcn_mfma_f32_16x16x32_f16(a, bhi[ct], cc, 0, 0, 0);
            cc = __builtin_amdgcn_mfma_f32_16x16x32_f16(a, blo[ct], cc, 0, 0, 0);
            c[ct] = cc;
        }
        #pragma unroll
        for (int ct = 0; ct < 4; ++ct) {
            #pragma unroll
            for (int r = 0; r < 4; ++r) {
                const int node = tb + kg * 4 + r;
                if (node < N) {
                    const float v = c[ct][r] + bcol[ct];
                    const size_t idx = (size_t)node * H + ct * 16 + row;
                    x0[idx] = v;
                    xh[idx] = f2h(fmaxf(v, 0.f));   // relu pre-folded, fp16
                }
            }
        }
    }
}

// ------------- weight conversion to split fp16 (all layers, once) -------------
extern "C" __global__ void k_cvtw(const float* __restrict__ W1s,
    const float* __restrict__ W2s, bfraw* __restrict__ W1hi,
    bfraw* __restrict__ W1lo, bfraw* __restrict__ W2hi,
    bfraw* __restrict__ W2lo, int total)  // total = L*H*TWOH
{
    int i = blockIdx.x * blockDim.x + threadIdx.x;
    const int st = gridDim.x * blockDim.x;
    for (; i < total; i += st) {
        {
            const float w = W1s[i];
            const bfraw hb = f2h(w);
            W1hi[i] = hb;
            W1lo[i] = f2h(w - h2f(hb));
        }
        {
            const float w = W2s[i];
            const bfraw hb = f2h(w);
            W2hi[i] = hb;
            W2lo[i] = f2h(w - h2f(hb));
        }
    }
}

// ---------------- block-private bucket partition (pass A) ----------------
__device__ __forceinline__ void bput(int s, int d, unsigned* __restrict__ lcnt,
    unsigned* __restrict__ myTmp, unsigned* __restrict__ deg,
    int* __restrict__ oflow, unsigned* __restrict__ ocnt)
{
    const int b = d >> BSH;
    const unsigned pos = atomicAdd(&lcnt[b], 1u);   // LDS atomic
    if (pos < BCAP) {
        myTmp[b * BCAP + pos] = (unsigned)s | ((unsigned)(d & (BNODE - 1)) << 20);
    } else {
        const unsigned o = atomicAdd(ocnt, 1u);
        if (o < OCAP) {
            oflow[2 * o] = s; oflow[2 * o + 1] = d;
            atomicAdd(&deg[d], 1u);
        }
    }
}

extern "C" __global__ void __launch_bounds__(256) k_bucket(
    const int* __restrict__ src, const int* __restrict__ dst,
    unsigned* __restrict__ bcnt, unsigned* __restrict__ btmp,
    unsigned* __restrict__ deg, int* __restrict__ oflow,
    unsigned* __restrict__ ocnt, int E, int NBck)
{
    __shared__ unsigned lcnt[MAXNB];  // 8 KB (NBck <= 2048)
    for (int i = threadIdx.x; i < NBck; i += blockDim.x) lcnt[i] = 0u;
    __syncthreads();
    unsigned* __restrict__ myTmp = btmp + (size_t)blockIdx.x * NBck * BCAP;
    const int tid0 = blockIdx.x * blockDim.x + threadIdx.x;
    const int st = gridDim.x * blockDim.x;
    const int E4 = E >> 2;
    const int4* s4 = (const int4*)src;
    const int4* d4 = (const int4*)dst;
    for (int j = tid0; j < E4; j += st) {
        const int4 sv = s4[j];
        const int4 dv = d4[j];
        bput(sv.x, dv.x, lcnt, myTmp, deg, oflow, ocnt);
        bput(sv.y, dv.y, lcnt, myTmp, deg, oflow, ocnt);
        bput(sv.z, dv.z, lcnt, myTmp, deg, oflow, ocnt);
        bput(sv.w, dv.w, lcnt, myTmp, deg, oflow, ocnt);
    }
    for (int j = (E4 << 2) + tid0; j < E; j += st)
        bput(src[j], dst[j], lcnt, myTmp, deg, oflow, ocnt);
    __syncthreads();
    unsigned* __restrict__ myCnt = bcnt + (size_t)blockIdx.x * NBck;
    for (int i = threadIdx.x; i < NBck; i += blockDim.x) {
        const unsigned c = lcnt[i];
        myCnt[i] = (c < BCAP) ? c : BCAP;
    }
}

// ---------------- per-bucket degree histogram ----------------
extern "C" __global__ void __launch_bounds__(256) k_bhist(
    const unsigned* __restrict__ bcnt, const unsigned* __restrict__ btmp,
    unsigned* __restrict__ deg, int N, int NBck)
{
    __shared__ unsigned hist[BNODE];
    const int b = blockIdx.x;
    for (int i = threadIdx.x; i < BNODE; i += blockDim.x) hist[i] = 0u;
    __syncthreads();
    for (int blk = threadIdx.x; blk < NBLK_PART; blk += blockDim.x) {
        const unsigned cnt = bcnt[(size_t)blk * NBck + b];
        const unsigned* p = btmp + ((size_t)blk * NBck + b) * BCAP;
        for (unsigned j = 0; j < cnt; ++j)
            atomicAdd(&hist[p[j] >> 20], 1u);
    }
    __syncthreads();
    const int base = b << BSH;
    for (int i = threadIdx.x; i < BNODE; i += blockDim.x)
        if (base + i < N) {
            const unsigned h = hist[i];
            if (h) atomicAdd(&deg[base + i], h);
        }
}

extern "C" __global__ void k_scan1(const unsigned* __restrict__ deg,
    unsigned* __restrict__ indptr, unsigned* __restrict__ bsum, int N)
{
    __shared__ unsigned s[256];
    const int tid = threadIdx.x;
    const int base = blockIdx.x * 1024 + tid * 4;
    unsigned d[4];
    #pragma unroll
    for (int j = 0; j < 4; ++j)
        d[j] = (base + j < N) ? ((deg[base + j] + 7u) & ~7u) : 0u;  // pad to 8
    unsigned t = d[0] + d[1] + d[2] + d[3];
    s[tid] = t;
    __syncthreads();
    for (int o = 1; o < 256; o <<= 1) {
        unsigned v = (tid >= o) ? s[tid - o] : 0u;
        __syncthreads();
        s[tid] += v;
        __syncthreads();
    }
    unsigned run = (tid == 0) ? 0u : s[tid - 1];
    if (tid == 255) bsum[blockIdx.x] = s[255];
    #pragma unroll
    for (int j = 0; j < 4; ++j) {
        if (base + j < N) indptr[base + j] = run;
        run += d[j];
    }
}

// scan2 + out-init fused (out[g] = bout[0]; later pool adds are commutative)
extern "C" __global__ void k_scan2(unsigned* bsum, int nb,
    unsigned* __restrict__ indptr, int N,
    const float* __restrict__ bout, float* __restrict__ out)
{
    if (threadIdx.x < NGRAPH) out[threadIdx.x] = bout[0];
    if (threadIdx.x == 0) {
        unsigned run = 0;
        for (int i = 0; i < nb; ++i) { unsigned v = bsum[i]; bsum[i] = run; run += v; }
        indptr[N] = run;  // total padded edges
    }
}

extern "C" __global__ void k_scan3(unsigned* __restrict__ indptr,
    const unsigned* __restrict__ bsum, unsigned* __restrict__ cursor, int N)
{
    const int base = blockIdx.x * 1024 + threadIdx.x * 4;
    const unsigned boff = bsum[blockIdx.x];
    #pragma unroll
    for (int j = 0; j < 4; ++j) {
        const int idx = base + j;
        if (idx < N) {
            const unsigned v = indptr[idx] + boff;
            indptr[idx] = v;
            cursor[idx] = v;
        }
    }
}

// ---------------- per-bucket scatter to final CSR (pass B) ----------------
extern "C" __global__ void __launch_bounds__(256) k_bscat(
    const unsigned* __restrict__ bcnt, const unsigned* __restrict__ btmp,
    const unsigned* __restrict__ indptr, unsigned* __restrict__ cursor,
    int* __restrict__ esrc, int N, int NBck)
{
    __shared__ unsigned lcur[BNODE];
    const int b = blockIdx.x;
    const int base = b << BSH;
    for (int i = threadIdx.x; i < BNODE; i += blockDim.x)
        lcur[i] = (base + i < N) ? indptr[base + i] : 0u;
    __syncthreads();
    for (int blk = threadIdx.x; blk < NBLK_PART; blk += blockDim.x) {
        const unsigned cnt = bcnt[(size_t)blk * NBck + b];
        const unsigned* p = btmp + ((size_t)blk * NBck + b) * BCAP;
        for (unsigned j = 0; j < cnt; ++j) {
            const unsigned e = p[j];
            const unsigned pos = atomicAdd(&lcur[e >> 20], 1u);
            esrc[pos] = (int)(e & 0xFFFFFu);
        }
    }
    __syncthreads();
    for (int i = threadIdx.x; i < BNODE; i += blockDim.x)
        if (base + i < N) cursor[base + i] = lcur[i];
}

// overflow edges (expected none) via global cursor
extern "C" __global__ void k_over(const int* __restrict__ oflow,
    const unsigned* __restrict__ ocnt, unsigned* __restrict__ cursor,
    int* __restrict__ esrc)
{
    unsigned n = *ocnt; if (n > OCAP) n = OCAP;
    int i = blockIdx.x * blockDim.x + threadIdx.x;
    const int st = gridDim.x * blockDim.x;
    for (; (unsigned)i < n; i += st) {
        const int s = oflow[2 * i], d = oflow[2 * i + 1];
        const unsigned pos = atomicAdd(&cursor[d], 1u);
        esrc[pos] = s;
    }
}

// fill padded slots with sentinel N (zero row)
extern "C" __global__ void k_pad(const unsigned* __restrict__ cursor,
    const unsigned* __restrict__ indptr, int* __restrict__ esrc, int N)
{
    int n = blockIdx.x * blockDim.x + threadIdx.x;
    const int st = gridDim.x * blockDim.x;
    for (; n < N; n += st) {
        const unsigned end = indptr[n + 1];
        for (unsigned p = cursor[n]; p < end; ++p) esrc[p] = N;
    }
}

// --- gather: hpreh = fp16((1+eps)*x0 + sum xh[src]) ---
// node-per-16-lane-group: 4 nodes/wave, 8 edges in flight per group per iter,
// no cross-lane reduce. degrees padded to 8.
extern "C" __global__ void __launch_bounds__(256) k_agg(
    const float* __restrict__ x0, const bfraw* __restrict__ xh,
    const int* __restrict__ esrc, const unsigned* __restrict__ indptr,
    const float* __restrict__ epsp, bfraw* __restrict__ hpreh, int N)
{
    const int lane = threadIdx.x & 63;
    const int grp = lane >> 4;          // 0..3 : node within the wave
    const int fi = (lane & 15) << 2;    // feature base (4 features)
    const int wpb = blockDim.x >> 6;
    const int wid = blockIdx.x * wpb + (threadIdx.x >> 6);
    const int wstride = gridDim.x * wpb;
    const float ep = 1.f + epsp[0];
    for (int nb = wid << 2; nb < N; nb += wstride << 2) {
        const int n = nb + grp;
        const bool act = (n < N);
        unsigned s0 = 0, s1 = 0;
        if (act) { s0 = indptr[n]; s1 = indptr[n + 1]; }  // (s1-s0)%8==0
        float a0 = 0.f, a1 = 0.f, a2 = 0.f, a3 = 0.f;
        for (unsigned e = s0; e < s1; e += 8) {
            const int4 ia = *(const int4*)&esrc[e];
            const int4 ib = *(const int4*)&esrc[e + 4];
            uint2 r0 = *(const uint2*)&xh[(size_t)ia.x * H + fi];
            uint2 r1 = *(const uint2*)&xh[(size_t)ia.y * H + fi];
            uint2 r2 = *(const uint2*)&xh[(size_t)ia.z * H + fi];
            uint2 r3 = *(const uint2*)&xh[(size_t)ia.w * H + fi];
            uint2 r4 = *(const uint2*)&xh[(size_t)ib.x * H + fi];
            uint2 r5 = *(const uint2*)&xh[(size_t)ib.y * H + fi];
            uint2 r6 = *(const uint2*)&xh[(size_t)ib.z * H + fi];
            uint2 r7 = *(const uint2*)&xh[(size_t)ib.w * H + fi];
            const __half2 s01 =
                __hadd2(__hadd2(__hadd2(u2h2(r0.x), u2h2(r1.x)),
                                __hadd2(u2h2(r2.x), u2h2(r3.x))),
                        __hadd2(__hadd2(u2h2(r4.x), u2h2(r5.x)),
                                __hadd2(u2h2(r6.x), u2h2(r7.x))));
            const __half2 s23 =
                __hadd2(__hadd2(__hadd2(u2h2(r0.y), u2h2(r1.y)),
                                __hadd2(u2h2(r2.y), u2h2(r3.y))),
                        __hadd2(__hadd2(u2h2(r4.y), u2h2(r5.y)),
                                __hadd2(u2h2(r6.y), u2h2(r7.y))));
            const float2 f01 = __half22float2(s01);
            const float2 f23 = __half22float2(s23);
            a0 += f01.x; a1 += f01.y; a2 += f23.x; a3 += f23.y;
        }
        if (act) {
            const float4 self = *(const float4*)&x0[(size_t)n * H + fi];
            ushort4 o;
            o.x = f2h(ep * self.x + a0);
            o.y = f2h(ep * self.y + a1);
            o.z = f2h(ep * self.z + a2);
            o.w = f2h(ep * self.w + a3);
            *(ushort4*)&hpreh[(size_t)n * H + fi] = o;
        }
    }
}

// --- MFMA GEMM1 + BN stats: h1h[N,128] = fp16(hpreh @ W1 + b1) ---
// A single fp16, W split fp16 (hi+lo): 2 MFMAs per (A,W). Each wave: half cols.
extern "C" __global__ void __launch_bounds__(256) k_gemm1(
    const bfraw* __restrict__ hpreh,
    const bfraw* __restrict__ W1hi, const bfraw* __restrict__ W1lo,
    const float* __restrict__ b1, bfraw* __restrict__ h1h,
    double* __restrict__ gsum, double* __restrict__ gsq, int N)
{
    __shared__ float ss[TWOH], sq[TWOH];
    if (threadIdx.x < TWOH) { ss[threadIdx.x] = 0.f; sq[threadIdx.x] = 0.f; }
    __syncthreads();
    const int lane = threadIdx.x & 63;
    const int row = lane & 15;   // A row / B col / D col
    const int kg  = lane >> 4;   // k-group
    const int wpb = blockDim.x >> 6;
    const int wid = blockIdx.x * wpb + (threadIdx.x >> 6);
    const int wstride = gridDim.x * wpb;
    const int half = wid & 1;          // which 64 of the 128 cols
    const int cb = half * 4;           // col-tile base
    // preload B fragments: 2 k-chunks x 4 col-tiles, fp16 hi+lo
    v8h bhi[2][4], blo[2][4];
    #pragma unroll
    for (int kc = 0; kc < 2; ++kc)
        #pragma unroll
        for (int ct = 0; ct < 4; ++ct) {
            v8h bh, bl;
            #pragma unroll
            for (int i = 0; i < 8; ++i) {
                const int idx = (kc * 32 + kg * 8 + i) * TWOH + (cb + ct) * 16 + row;
                bh[i] = (_Float16)__ushort_as_half(W1hi[idx]);
                bl[i] = (_Float16)__ushort_as_half(W1lo[idx]);
            }
            bhi[kc][ct] = bh; blo[kc][ct] = bl;
        }
    float bcol[4];
    #pragma unroll
    for (int ct = 0; ct < 4; ++ct) bcol[ct] = b1[(cb + ct) * 16 + row];

    const int tiles = (N + 15) >> 4;
    const int tstride = wstride >> 1;
    float sacc[4], qacc[4];
    #pragma unroll
    for (int ct = 0; ct < 4; ++ct) { sacc[ct] = 0.f; qacc[ct] = 0.f; }

    for (int t = wid >> 1; t < tiles; t += tstride) {
        const int tb = t << 4;
        int nA = tb + row; if (nA >= N) nA = N - 1;
        h8cast a0c, a1c;
        a0c.q = *(const uint4*)&hpreh[(size_t)nA * H + kg * 8];
        a1c.q = *(const uint4*)&hpreh[(size_t)nA * H + 32 + kg * 8];
        const v8h a0 = a0c.h;
        const v8h a1 = a1c.h;
        v4f c[4];
        #pragma unroll
        for (int ct = 0; ct < 4; ++ct) {
            v4f cc = (v4f){0.f, 0.f, 0.f, 0.f};
            cc = __builtin_amdgcn_mfma_f32_16x16x32_f16(a0, bhi[0][ct], cc, 0, 0, 0);
            cc = __builtin_amdgcn_mfma_f32_16x16x32_f16(a1, bhi[1][ct], cc, 0, 0, 0);
            cc = __builtin_amdgcn_mfma_f32_16x16x32_f16(a0, blo[0][ct], cc, 0, 0, 0);
            cc = __builtin_amdgcn_mfma_f32_16x16x32_f16(a1, blo[1][ct], cc, 0, 0, 0);
            c[ct] = cc;
        }
        #pragma unroll
        for (int ct = 0; ct < 4; ++ct) {
            #pragma unroll
            for (int r = 0; r < 4; ++r) {
                const int node = tb + kg * 4 + r;  // D row
                if (node < N) {
                    const float v = c[ct][r] + bcol[ct];
                    h1h[(size_t)node * TWOH + (cb + ct) * 16 + row] = f2h(v);
                    sacc[ct] += v;
                    qacc[ct] += v * v;
                }
            }
        }
    }
    #pragma unroll
    for (int ct = 0; ct < 4; ++ct) {
        float s = sacc[ct];
        s += __shfl_xor(s, 16); s += __shfl_xor(s, 32);
        float q = qacc[ct];
        q += __shfl_xor(q, 16); q += __shfl_xor(q, 32);
        if (kg == 0) {
            atomicAdd(&ss[(cb + ct) * 16 + row], s);
            atomicAdd(&sq[(cb + ct) * 16 + row], q);
        }
    }
    __syncthreads();
    if (threadIdx.x < TWOH) {
        atomicAdd(&gsum[threadIdx.x], (double)ss[threadIdx.x]);
        atomicAdd(&gsq[threadIdx.x], (double)sq[threadIdx.x]);
    }
}

// --- MFMA GEMM2 + BN finalize (in prologue) + BN/ReLU + residual ---
extern "C" __global__ void __launch_bounds__(256) k_gemm2(
    const bfraw* __restrict__ h1h,
    const double* __restrict__ gsum, const double* __restrict__ gsq,
    const float* __restrict__ gamma, const float* __restrict__ beta,
    const bfraw* __restrict__ W2hi, const bfraw* __restrict__ W2lo,
    const float* __restrict__ b2, float* __restrict__ x0,
    bfraw* __restrict__ xh, int N)
{
    __shared__ float scl[TWOH], shl[TWOH];  // 1 KB
    if (threadIdx.x < TWOH) {
        const int j = threadIdx.x;
        const double mu = gsum[j] / N;
        const double var = gsq[j] / N - mu * mu;
        const float sc = gamma[j] * rsqrtf(fmaxf((float)var, 0.f) + 1e-5f);
        scl[j] = sc;
        shl[j] = beta[j] - (float)mu * sc;
    }
    __syncthreads();
    const int lane = threadIdx.x & 63;
    const int row = lane & 15;
    const int kg  = lane >> 4;
    const int wpb = blockDim.x >> 6;
    const int wid = blockIdx.x * wpb + (threadIdx.x >> 6);
    const int wstride = gridDim.x * wpb;
    const int half = wid & 1;       // which 32 of the 64 cols
    const int cb = half * 2;        // col-tile base
    // preload B fragments: 4 k-chunks x 2 col-tiles, fp16 hi+lo
    v8h bhi[4][2], blo[4][2];
    #pragma unroll
    for (int kc = 0; kc < 4; ++kc)
        #pragma unroll
        for (int ct = 0; ct < 2; ++ct) {
            v8h bh, bl;
            #pragma unroll
            for (int i = 0; i < 8; ++i) {
                const int idx = (kc * 32 + kg * 8 + i) * H + (cb + ct) * 16 + row;
                bh[i] = (_Float16)__ushort_as_half(W2hi[idx]);
                bl[i] = (_Float16)__ushort_as_half(W2lo[idx]);
            }
            bhi[kc][ct] = bh; blo[kc][ct] = bl;
        }
    float bcol[2];
    #pragma unroll
    for (int ct = 0; ct < 2; ++ct) bcol[ct] = b2[(cb + ct) * 16 + row];
    // per-lane BN constants for this lane's 32 features (8 per k-chunk)
    float lsc[4][8], lsh[4][8];
    #pragma unroll
    for (int kc = 0; kc < 4; ++kc) {
        const int fb = kc * 32 + kg * 8;
        #pragma unroll
        for (int i = 0; i < 8; ++i) { lsc[kc][i] = scl[fb + i]; lsh[kc][i] = shl[fb + i]; }
    }

    const int tiles = (N + 15) >> 4;
    const int tstride = wstride >> 1;

    for (int t = wid >> 1; t < tiles; t += tstride) {
        const int tb = t << 4;
        int nA = tb + row; if (nA >= N) nA = N - 1;
        v8h a[4];
        #pragma unroll
        for (int kc = 0; kc < 4; ++kc) {
            const int fb = kc * 32 + kg * 8;
            h8cast hc;
            hc.q = *(const uint4*)&h1h[(size_t)nA * TWOH + fb];
            v8h va;
            #pragma unroll
            for (int i = 0; i < 8; ++i) {
                const float hv = (float)hc.h[i];
                va[i] = (_Float16)fmaxf(hv * lsc[kc][i] + lsh[kc][i], 0.f);
            }
            a[kc] = va;
        }
        v4f c[2];
        #pragma unroll
        for (int ct = 0; ct < 2; ++ct) {
            v4f cc = (v4f){0.f, 0.f, 0.f, 0.f};
            #pragma unroll
            for (int kc = 0; kc < 4; ++kc) {
                cc = __builtin_amdgcn_mfma_f32_16x16x32_f16(a[kc], bhi[kc][ct], cc, 0, 0, 0);
                cc = __builtin_amdgcn_mfma_f32_16x16x32_f16(a[kc], blo[kc][ct], cc, 0, 0, 0);
            }
            c[ct] = cc;
        }
        #pragma unroll
        for (int ct = 0; ct < 2; ++ct) {
            #pragma unroll
            for (int r = 0; r < 4; ++r) {
                const int node = tb + kg * 4 + r;
                if (node < N) {
                    const size_t idx = (size_t)node * H + (cb + ct) * 16 + row;
                    const float v = x0[idx] + c[ct][r] + bcol[ct];
                    x0[idx] = v;
                    xh[idx] = f2h(fmaxf(v, 0.f));   // relu pre-folded, fp16
                }
            }
        }
    }
}

// segment-sum pooling: batch is SORTED. Each wave owns a contiguous node slab;
// lane l accumulates feature l; flush (reduce+atomic) only at graph boundaries.
extern "C" __global__ void __launch_bounds__(256) k_pool(
    const float* __restrict__ x0, const int* __restrict__ batch,
    const float* __restrict__ Wout, float* __restrict__ out, int N)
{
    const int lane = threadIdx.x & 63;
    const int wpb = blockDim.x >> 6;
    const int gw = blockIdx.x * wpb + (threadIdx.x >> 6);
    const int nw = gridDim.x * wpb;
    const int per = (N + nw - 1) / nw;
    const int n0 = gw * per;
    int n1 = n0 + per; if (n1 > N) n1 = N;
    if (n0 >= N) return;
    const float wv = Wout[lane];
    int cur = batch[n0];
    float acc = 0.f;
    for (int n = n0; n < n1; ++n) {
        const int g = batch[n];
        if (g != cur) {
            float v = acc * wv;
            #pragma unroll
            for (int o = 32; o > 0; o >>= 1) v += __shfl_down(v, o);
            if (lane == 0) atomicAdd(&out[cur], v);
            cur = g;
            acc = 0.f;
        }
        acc += x0[(size_t)n * H + lane];
    }
    float v = acc * wv;
    #pragma unroll
    for (int o = 32; o > 0; o >>= 1) v += __shfl_down(v, o);
    if (lane == 0) atomicAdd(&out[cur], v);
}

// ---------------- host driver ----------------
extern "C" void kernel_launch(void* const* d_in, const int* in_sizes, int n_in,
                              void* d_out, int out_size, void* d_ws, size_t ws_size,
                              hipStream_t stream)
{
    const float* x     = (const float*)d_in[0];
    const int*   ei    = (const int*)d_in[1];   // int32 per harness conversion
    const int*   batch = (const int*)d_in[2];   // int32 per harness conversion
    const float* Win   = (const float*)d_in[3];
    const float* bin   = (const float*)d_in[4];
    const float* W1s   = (const float*)d_in[5];
    const float* b1s   = (const float*)d_in[6];
    const float* gam   = (const float*)d_in[7];
    const float* bet   = (const float*)d_in[8];
    const float* W2s   = (const float*)d_in[9];
    const float* b2s   = (const float*)d_in[10];
    const float* epss  = (const float*)d_in[11];
    const float* Wout  = (const float*)d_in[12];
    const float* bout  = (const float*)d_in[13];

    const int N = in_sizes[0] / CIN;
    const int E = in_sizes[1] / 2;
    const int L = in_sizes[11];
    const int* src = ei;
    const int* dst = ei + E;
    const int NB = (N + BNODE - 1) >> BSH;   // final buckets (<= MAXNB)

    // workspace layout
    char* ws = (char*)d_ws;
    size_t off = 0;
    auto take = [&](size_t bytes) {
        void* p = ws + off;
        off += (bytes + 255) & ~(size_t)255;
        return p;
    };
    float*    x0     = (float*)take((size_t)N * H * 4);
    bfraw*    xh     = (bfraw*)take((size_t)(N + 1) * H * 2);  // fp16, +1 zero row
    bfraw*    hpreh  = (bfraw*)take((size_t)N * H * 2);        // fp16
    bfraw*    h1h    = (bfraw*)take((size_t)N * TWOH * 2);     // fp16
    unsigned* deg    = (unsigned*)take((size_t)N * 4);
    unsigned* indptr = (unsigned*)take((size_t)(N + 1) * 4);
    unsigned* cursor = (unsigned*)take((size_t)N * 4);
    int*      esrc   = (int*)take((size_t)(E + 8 * (N + 1)) * 4);  // padded to 8
    unsigned* bsum   = (unsigned*)take(4096);
    double*   gsumAll = (double*)take((size_t)8 * TWOH * 8 * 2); // per-layer gsum+gsq
    bfraw*    W1hi   = (bfraw*)take((size_t)L * H * TWOH * 2);
    bfraw*    W1lo   = (bfraw*)take((size_t)L * H * TWOH * 2);
    bfraw*    W2hi   = (bfraw*)take((size_t)L * TWOH * H * 2);
    bfraw*    W2lo   = (bfraw*)take((size_t)L * TWOH * H * 2);
    unsigned* bcnt   = (unsigned*)take((size_t)NBLK_PART * NB * 4);
    unsigned* btmp   = (unsigned*)take((size_t)NBLK_PART * NB * BCAP * 4);
    int*      oflow  = (int*)take((size_t)OCAP * 2 * 4);
    unsigned* ocnt   = (unsigned*)take(256);
    (void)ws_size; (void)n_in; (void)out_size;

    hipMemsetAsync(deg, 0, (size_t)N * 4, stream);
    hipMemsetAsync(ocnt, 0, 4, stream);
    hipMemsetAsync(xh + (size_t)N * H, 0, H * 2, stream);  // sentinel zero row
    hipMemsetAsync(gsumAll, 0, (size_t)8 * TWOH * 8 * 2, stream);  // all layers
    k_input_gemm<<<512, 256, 0, stream>>>(x, Win, bin, x0, xh, N);
    k_cvtw<<<256, 256, 0, stream>>>(W1s, W2s, W1hi, W1lo, W2hi, W2lo, L * H * TWOH);
    k_bucket<<<NBLK_PART, 256, 0, stream>>>(src, dst, bcnt, btmp, deg, oflow, ocnt, E, NB);
    k_bhist<<<NB, 256, 0, stream>>>(bcnt, btmp, deg, N, NB);
    const int nb = (N + 1023) / 1024;
    k_scan1<<<nb, 256, 0, stream>>>(deg, indptr, bsum, N);
    k_scan2<<<1, 64, 0, stream>>>(bsum, nb, indptr, N, bout, (float*)d_out);
    k_scan3<<<nb, 256, 0, stream>>>(indptr, bsum, cursor, N);
    k_bscat<<<NB, 256, 0, stream>>>(bcnt, btmp, indptr, cursor, esrc, N, NB);
    k_over<<<32, 256, 0, stream>>>(oflow, ocnt, cursor, esrc);
    k_pad<<<512, 256, 0, stream>>>(cursor, indptr, esrc, N);

    for (int l = 0; l < L; ++l) {
        double* gsum = gsumAll + (size_t)l * 2 * TWOH;
        double* gsq  = gsum + TWOH;
        k_agg<<<2048, 256, 0, stream>>>(x0, xh, esrc, indptr, epss + l, hpreh, N);
        k_gemm1<<<512, 256, 0, stream>>>(hpreh,
            W1hi + (size_t)l * H * TWOH, W1lo + (size_t)l * H * TWOH,
            b1s + (size_t)l * TWOH, h1h, gsum, gsq, N);
        k_gemm2<<<512, 256, 0, stream>>>(h1h, gsum, gsq,
            gam + (size_t)l * TWOH, bet + (size_t)l * TWOH,
            W2hi + (size_t)l * TWOH * H, W2lo + (size_t)l * TWOH * H,
            b2s + (size_t)l * H, x0, xh, N);
    }

    k_pool<<<512, 256, 0, stream>>>(x0, batch, Wout, (float*)d_out, N);
}